// Round 2
// baseline (1263.424 us; speedup 1.0000x reference)
//
#include <hip/hip_runtime.h>
#include <cstdint>
#include <cstddef>

#define S_LEN 2048
#define HID   3072
#define NH    24
#define NKV   8
#define HD    128
#define ROT   96
#define OPSZ  5120   // NH*HD + 2*NKV*HD
#define NREP  3      // NH/NKV
#define SCALING 0.08838834764831845f

typedef _Float16 f16;
typedef float f32x4 __attribute__((ext_vector_type(4)));
typedef _Float16 f16x8 __attribute__((ext_vector_type(8)));
typedef _Float16 f16x4 __attribute__((ext_vector_type(4)));

#define GLOBAL_AS __attribute__((address_space(1)))
#define LDS_AS    __attribute__((address_space(3)))

// ---------------- cast fp32 -> fp16 (4 elems/thread) ----------------
__global__ void k_cast4(const float* __restrict__ in, f16* __restrict__ out, int n4) {
  int i = blockIdx.x * blockDim.x + threadIdx.x;
  if (i >= n4) return;
  float4 v = reinterpret_cast<const float4*>(in)[i];
  f16x4 o = {(f16)v.x, (f16)v.y, (f16)v.z, (f16)v.w};
  reinterpret_cast<f16x4*>(out)[i] = o;
}

// ---------------- GEMM building blocks ----------------
__device__ __forceinline__ void stage_async(const f16* __restrict__ G, int ld, int m0, int k0,
                                            f16* __restrict__ Ls) {
  int t = threadIdx.x;
  int lane = t & 63, w = t >> 6;
#pragma unroll
  for (int j = 0; j < 2; ++j) {
    int rowBase = w * 16 + j * 64;            // wave-uniform
    int row = rowBase + (lane >> 2);
    int seg = lane & 3;
    const f16* gp = G + (size_t)(m0 + row) * ld + k0 + seg * 8;
    f16* lp = Ls + rowBase * 32;              // wave-uniform LDS base
    __builtin_amdgcn_global_load_lds((GLOBAL_AS const void*)gp, (LDS_AS void*)lp, 16, 0, 0);
  }
}

__device__ __forceinline__ void mma_tile(const f16* __restrict__ As, const f16* __restrict__ Bs,
                                         f32x4 acc[4][4], int wm, int wn, int lrow, int quad) {
  f16x8 a[4], b[4];
#pragma unroll
  for (int mi = 0; mi < 4; ++mi)
    a[mi] = *reinterpret_cast<const f16x8*>(As + (wm + mi * 16 + lrow) * 32 + quad * 8);
#pragma unroll
  for (int ni = 0; ni < 4; ++ni)
    b[ni] = *reinterpret_cast<const f16x8*>(Bs + (wn + ni * 16 + lrow) * 32 + quad * 8);
#pragma unroll
  for (int mi = 0; mi < 4; ++mi)
#pragma unroll
    for (int ni = 0; ni < 4; ++ni)
      acc[mi][ni] = __builtin_amdgcn_mfma_f32_16x16x32_f16(a[mi], b[ni], acc[mi][ni], 0, 0, 0);
}

// ---------------- QKV GEMM ----------------
__global__ __launch_bounds__(256) void k_gemm_qkv(const f16* __restrict__ A,
                                                  const f16* __restrict__ B,
                                                  f16* __restrict__ C) {
  int m0 = blockIdx.y * 128, n0 = blockIdx.x * 128;
  __shared__ __align__(16) f16 As[128 * 32];
  __shared__ __align__(16) f16 Bs[128 * 32];
  f32x4 acc[4][4] = {};
  int t = threadIdx.x, lane = t & 63, w = t >> 6;
  int wm = (w >> 1) * 64, wn = (w & 1) * 64, lrow = lane & 15, quad = lane >> 4;
  for (int kb = 0; kb < HID / 32; ++kb) {
    stage_async(A, HID, m0, kb * 32, As);
    stage_async(B, HID, n0, kb * 32, Bs);
    __syncthreads();
    mma_tile(As, Bs, acc, wm, wn, lrow, quad);
    __syncthreads();
  }
#pragma unroll
  for (int mi = 0; mi < 4; ++mi)
#pragma unroll
    for (int ni = 0; ni < 4; ++ni)
#pragma unroll
      for (int r = 0; r < 4; ++r) {
        int row = m0 + wm + mi * 16 + quad * 4 + r;
        int col = n0 + wn + ni * 16 + lrow;
        C[(size_t)row * OPSZ + col] = (f16)acc[mi][ni][r];
      }
}

// ---------------- out proj ----------------
__global__ __launch_bounds__(256) void k_gemm_out(const f16* __restrict__ A,
                                                  const f16* __restrict__ B,
                                                  float* __restrict__ C) {
  int m0 = blockIdx.y * 128, n0 = blockIdx.x * 128;
  __shared__ __align__(16) f16 As[128 * 32];
  __shared__ __align__(16) f16 Bs[128 * 32];
  f32x4 acc[4][4] = {};
  int t = threadIdx.x, lane = t & 63, w = t >> 6;
  int wm = (w >> 1) * 64, wn = (w & 1) * 64, lrow = lane & 15, quad = lane >> 4;
  for (int kb = 0; kb < HID / 32; ++kb) {
    stage_async(A, HID, m0, kb * 32, As);
    stage_async(B, HID, n0, kb * 32, Bs);
    __syncthreads();
    mma_tile(As, Bs, acc, wm, wn, lrow, quad);
    __syncthreads();
  }
#pragma unroll
  for (int mi = 0; mi < 4; ++mi)
#pragma unroll
    for (int ni = 0; ni < 4; ++ni)
#pragma unroll
      for (int r = 0; r < 4; ++r) {
        int row = m0 + wm + mi * 16 + quad * 4 + r;
        int col = n0 + wn + ni * 16 + lrow;
        C[(size_t)row * HID + col] = acc[mi][ni][r];
      }
}

// ---------------- RoPE on Q and K heads ----------------
__global__ void k_rope(const f16* __restrict__ qkv, const float* __restrict__ cosd,
                       const float* __restrict__ sind, f16* __restrict__ Q,
                       f16* __restrict__ Kc) {
  int idx = blockIdx.x * 256 + threadIdx.x;
  int d = idx & 127;
  int s = (idx >> 7) & (S_LEN - 1);
  int hh = idx >> 18;
  int srcCol = (hh < NH) ? hh * HD + d : HID + (hh - NH) * HD + d;
  float x = (float)qkv[(size_t)s * OPSZ + srcCol];
  float r;
  if (d < ROT) {
    float c = cosd[s * ROT + d], sn = sind[s * ROT + d];
    int pd = (d < 48) ? d + 48 : d - 48;
    float px = (float)qkv[(size_t)s * OPSZ + srcCol - d + pd];
    r = x * c + ((d < 48) ? -px : px) * sn;
  } else {
    r = x;
  }
  f16 o = (f16)r;
  if (hh < NH) Q[((size_t)hh * S_LEN + s) * HD + d] = o;
  else         Kc[((size_t)(hh - NH) * S_LEN + s) * HD + d] = o;
}

// ---------------- V transpose: Vt[8,128,2048] ----------------
__global__ void k_vt(const f16* __restrict__ qkv, f16* __restrict__ Vt) {
  __shared__ f16 tile[32][33];
  int s0 = blockIdx.x * 32, d0 = blockIdx.y * 32, kv = blockIdx.z;
  int tx = threadIdx.x & 31, ty = threadIdx.x >> 5;
#pragma unroll
  for (int i = 0; i < 4; ++i)
    tile[ty + i * 8][tx] = qkv[(size_t)(s0 + ty + i * 8) * OPSZ + 4096 + kv * HD + d0 + tx];
  __syncthreads();
#pragma unroll
  for (int i = 0; i < 4; ++i)
    Vt[((size_t)kv * HD + d0 + ty + i * 8) * S_LEN + s0 + tx] = tile[tx][ty + i * 8];
}

// ---------------- fused attention ----------------
// Swizzled stage: NR rows of RB bytes from row-major G (leading dim ld, f16 elems)
// into LDS with 16B-segment XOR swizzle seg' = seg ^ (row&7). LDS dest is linear
// (wave-uniform base + lane*16B, as global_load_lds requires); the swizzle is
// applied by permuting the per-lane GLOBAL source (rule: both-sides-or-neither).
template <int RB, int NR>
__device__ __forceinline__ void stage_swz(const f16* __restrict__ G, int ld,
                                          f16* __restrict__ Ls) {
  constexpr int RPI = 1024 / RB;          // rows per 1024B wave issue
  constexpr int SEGS = RB / 16;           // 16B segments per row
  constexpr int ISSUES = (NR * RB) / 4096;
  int t = threadIdx.x, lane = t & 63, w = t >> 6;
#pragma unroll
  for (int j = 0; j < ISSUES; ++j) {
    int rowBase = (w * ISSUES + j) * RPI;  // wave-uniform
    int row = rowBase + lane / SEGS;
    int gseg = (lane % SEGS) ^ (row & 7);
    const f16* gp = G + (size_t)row * ld + gseg * 8;
    f16* lp = Ls + rowBase * (RB / 2);     // wave-uniform LDS base
    __builtin_amdgcn_global_load_lds((GLOBAL_AS const void*)gp, (LDS_AS void*)lp, 16, 0, 0);
  }
}

// Per (head h, 128-row block bm):
//   pass1: online row-max m and denom l over KV tiles of 64 (QK^T via MFMA)
//   pass2: recompute S, P = exp(S-m)/l, write P fp32 to attn, P f16 -> LDS, PV MFMA
//   tail:  write AO (f16) and zero-fill cols >= (bm+1)*128
__global__ __launch_bounds__(256, 2) void k_attn(const f16* __restrict__ Q,
                                                 const f16* __restrict__ Kc,
                                                 const f16* __restrict__ Vt,
                                                 float* __restrict__ attn,
                                                 f16* __restrict__ AO) {
  __shared__ __align__(16) f16 Ks[64 * 128];     // [t 64][d 128] swz  16KB
  __shared__ __align__(16) f16 Vs[2][128 * 64];  // [d 128][t 64] swz  2x16KB
  __shared__ __align__(16) f16 Ps[128 * 64];     // [s 128][t 64] swz  16KB (stats overlay in pass1)

  // heavy/light interleave: pairs (15-q, q) so all 384 blocks co-resident, balanced
  int bx = blockIdx.x;
  int pairIdx = bx >> 1;
  int h = pairIdx / 8;
  int q8 = pairIdx & 7;
  int bm = (bx & 1) ? q8 : 15 - q8;
  int m0 = bm * 128;
  int nt = 2 * (bm + 1);   // 64-wide KV tiles covering cols 0 .. (bm+1)*128-1

  const f16* Qh = Q + (size_t)h * S_LEN * HD;
  const f16* Kh = Kc + (size_t)(h / NREP) * S_LEN * HD;
  const f16* Vh = Vt + (size_t)(h / NREP) * HD * S_LEN;
  float* attnH = attn + (size_t)h * S_LEN * S_LEN;

  int t = threadIdx.x, lane = t & 63, w = t >> 6;
  int wm = (w >> 1) * 64;        // row half owned by wave pair
  int wn = (w & 1) * 32;         // col half within 64-wide S tile
  int wn2 = (w & 1) * 64;        // col half within 128-wide PV output
  int lrow = lane & 15, quad = lane >> 4;

  // Q fragments held in registers for the whole kernel (16B coalesced loads)
  f16x8 qf[4][4];
#pragma unroll
  for (int kq = 0; kq < 4; ++kq)
#pragma unroll
    for (int mi = 0; mi < 4; ++mi)
      qf[kq][mi] = *reinterpret_cast<const f16x8*>(
          Qh + (size_t)(m0 + wm + mi * 16 + lrow) * HD + kq * 32 + quad * 8);

  stage_swz<256, 64>(Kh, HD, Ks);  // K tile 0

  float m_run[4][4], l_run[4][4];
#pragma unroll
  for (int mi = 0; mi < 4; ++mi)
#pragma unroll
    for (int r = 0; r < 4; ++r) { m_run[mi][r] = -1e30f; l_run[mi][r] = 0.f; }

  // ---------------- pass 1: row stats ----------------
  for (int kb = 0; kb < nt; ++kb) {
    __syncthreads();               // K(kb) arrived
    f32x4 sacc[4][2] = {};
    __builtin_amdgcn_s_setprio(1);
#pragma unroll
    for (int kq = 0; kq < 4; ++kq) {
      int kbyte = kq * 64 + quad * 16;
      f16x8 b[2];
#pragma unroll
      for (int ni = 0; ni < 2; ++ni) {
        int rowb = wn + ni * 16 + lrow;
        b[ni] = *reinterpret_cast<const f16x8*>(
            reinterpret_cast<const char*>(Ks) + rowb * 256 + (kbyte ^ ((rowb & 7) << 4)));
      }
#pragma unroll
      for (int mi = 0; mi < 4; ++mi)
#pragma unroll
        for (int ni = 0; ni < 2; ++ni)
          sacc[mi][ni] =
              __builtin_amdgcn_mfma_f32_16x16x32_f16(qf[kq][mi], b[ni], sacc[mi][ni], 0, 0, 0);
    }
    __builtin_amdgcn_s_setprio(0);
    __syncthreads();               // Ks consumed by all waves
    if (kb + 1 < nt) {
      stage_swz<256, 64>(Kh + (size_t)(kb + 1) * 64 * HD, HD, Ks);
    } else {
      stage_swz<256, 64>(Kh, HD, Ks);          // prefetch K(0) for pass 2
      stage_swz<128, 128>(Vh, S_LEN, Vs[0]);   // prefetch V(0)
    }
    int n0 = kb * 64;
#pragma unroll
    for (int mi = 0; mi < 4; ++mi)
#pragma unroll
      for (int r = 0; r < 4; ++r) {
        int rG = m0 + wm + mi * 16 + quad * 4 + r;
        float sv0, sv1;
        {
          int c0 = n0 + wn + lrow;
          float s0 = sacc[mi][0][r] * SCALING;
          sv0 = (c0 > rG) ? -1e30f : s0;
          int c1 = c0 + 16;
          float s1 = sacc[mi][1][r] * SCALING;
          sv1 = (c1 > rG) ? -1e30f : s1;
        }
        float tmax = fmaxf(sv0, sv1);
#pragma unroll
        for (int msk = 8; msk >= 1; msk >>= 1) tmax = fmaxf(tmax, __shfl_xor(tmax, msk));
        float mold = m_run[mi][r];
        float mnew = fmaxf(mold, tmax);
        float psum = __expf(sv0 - mnew) + __expf(sv1 - mnew);
#pragma unroll
        for (int msk = 8; msk >= 1; msk >>= 1) psum += __shfl_xor(psum, msk);
        l_run[mi][r] = l_run[mi][r] * __expf(mold - mnew) + psum;
        m_run[mi][r] = mnew;
      }
  }

  // combine wave-pair halves (cols 0-31 / 32-63 ownership) via LDS overlay on Ps
  {
    float* sm = reinterpret_cast<float*>(Ps);   // [2][128]
    float* sl = sm + 256;                       // [2][128]
    if (lrow == 0) {
#pragma unroll
      for (int mi = 0; mi < 4; ++mi)
#pragma unroll
        for (int r = 0; r < 4; ++r) {
          int rL = wm + mi * 16 + quad * 4 + r;
          sm[(w & 1) * 128 + rL] = m_run[mi][r];
          sl[(w & 1) * 128 + rL] = l_run[mi][r];
        }
    }
    __syncthreads();
#pragma unroll
    for (int mi = 0; mi < 4; ++mi)
#pragma unroll
      for (int r = 0; r < 4; ++r) {
        int rL = wm + mi * 16 + quad * 4 + r;
        float ma = sm[rL], mb = sm[128 + rL];
        float la = sl[rL], lb = sl[128 + rL];
        float mm = fmaxf(ma, mb);
        float ll = la * __expf(ma - mm) + lb * __expf(mb - mm);
        m_run[mi][r] = mm;
        l_run[mi][r] = 1.0f / ll;   // reuse as 1/l
      }
  }

  // ---------------- pass 2: P write + PV ----------------
  f32x4 oacc[4][4] = {};
  for (int kb = 0; kb < nt; ++kb) {
    __syncthreads();               // K(kb) in Ks, V(kb) in Vs[kb&1]; Ps free
    f32x4 sacc[4][2] = {};
    __builtin_amdgcn_s_setprio(1);
#pragma unroll
    for (int kq = 0; kq < 4; ++kq) {
      int kbyte = kq * 64 + quad * 16;
      f16x8 b[2];
#pragma unroll
      for (int ni = 0; ni < 2; ++ni) {
        int rowb = wn + ni * 16 + lrow;
        b[ni] = *reinterpret_cast<const f16x8*>(
            reinterpret_cast<const char*>(Ks) + rowb * 256 + (kbyte ^ ((rowb & 7) << 4)));
      }
#pragma unroll
      for (int mi = 0; mi < 4; ++mi)
#pragma unroll
        for (int ni = 0; ni < 2; ++ni)
          sacc[mi][ni] =
              __builtin_amdgcn_mfma_f32_16x16x32_f16(qf[kq][mi], b[ni], sacc[mi][ni], 0, 0, 0);
    }
    __builtin_amdgcn_s_setprio(0);
    __syncthreads();               // Ks consumed -> safe to restage
    if (kb + 1 < nt) {
      stage_swz<256, 64>(Kh + (size_t)(kb + 1) * 64 * HD, HD, Ks);
      stage_swz<128, 128>(Vh + (size_t)(kb + 1) * 64, S_LEN, Vs[(kb + 1) & 1]);
    }
    int n0 = kb * 64;
#pragma unroll
    for (int mi = 0; mi < 4; ++mi)
#pragma unroll
      for (int r = 0; r < 4; ++r) {
        int rL = wm + mi * 16 + quad * 4 + r;
        float mm = m_run[mi][r], il = l_run[mi][r];
#pragma unroll
        for (int ni = 0; ni < 2; ++ni) {
          int cL = wn + ni * 16 + lrow;
          int c = n0 + cL;
          float s = sacc[mi][ni][r] * SCALING;
          if (c > m0 + rL) s = -1e30f;
          float p = __expf(s - mm) * il;
          attnH[(size_t)(m0 + rL) * S_LEN + c] = p;
          *reinterpret_cast<f16*>(reinterpret_cast<char*>(Ps) + rL * 128 +
                                  ((cL * 2) ^ ((rL & 7) << 4))) = (f16)p;
        }
      }
    __syncthreads();               // Ps published; prefetch stages drained
    const f16* Vc = Vs[kb & 1];
    __builtin_amdgcn_s_setprio(1);
#pragma unroll
    for (int kq = 0; kq < 2; ++kq) {
      int kbyte = kq * 64 + quad * 16;
      f16x8 a[4], b[4];
#pragma unroll
      for (int mi = 0; mi < 4; ++mi) {
        int rowp = wm + mi * 16 + lrow;
        a[mi] = *reinterpret_cast<const f16x8*>(
            reinterpret_cast<const char*>(Ps) + rowp * 128 + (kbyte ^ ((rowp & 7) << 4)));
      }
#pragma unroll
      for (int ni = 0; ni < 4; ++ni) {
        int rowv = wn2 + ni * 16 + lrow;
        b[ni] = *reinterpret_cast<const f16x8*>(
            reinterpret_cast<const char*>(Vc) + rowv * 128 + (kbyte ^ ((rowv & 7) << 4)));
      }
#pragma unroll
      for (int mi = 0; mi < 4; ++mi)
#pragma unroll
        for (int ni = 0; ni < 4; ++ni)
          oacc[mi][ni] =
              __builtin_amdgcn_mfma_f32_16x16x32_f16(a[mi], b[ni], oacc[mi][ni], 0, 0, 0);
    }
    __builtin_amdgcn_s_setprio(0);
  }

  // AO epilogue
#pragma unroll
  for (int mi = 0; mi < 4; ++mi)
#pragma unroll
    for (int ni = 0; ni < 4; ++ni)
#pragma unroll
      for (int r = 0; r < 4; ++r) {
        int row = m0 + wm + mi * 16 + quad * 4 + r;
        int col = wn2 + ni * 16 + lrow;
        AO[(size_t)row * HID + h * HD + col] = (f16)oacc[mi][ni][r];
      }

  // zero-fill fully masked cols >= (bm+1)*128
  float4 z = {0.f, 0.f, 0.f, 0.f};
  for (int zt = bm + 1; zt < 16; ++zt) {
    float* outp = attnH + (size_t)m0 * S_LEN + zt * 128;
#pragma unroll
    for (int j = 0; j < 16; ++j) {
      int lin = t + 256 * j;
      int rowz = lin >> 5, seg = lin & 31;
      reinterpret_cast<float4*>(outp + (size_t)rowz * S_LEN)[seg] = z;
    }
  }
}

// ---------------- launch ----------------
extern "C" void kernel_launch(void* const* d_in, const int* in_sizes, int n_in,
                              void* d_out, int out_size, void* d_ws, size_t ws_size,
                              hipStream_t stream) {
  const float* hs    = (const float*)d_in[0];
  const float* cosd  = (const float*)d_in[1];
  const float* sind  = (const float*)d_in[2];
  // d_in[3] = attention_mask (causal by construction; unused)
  const float* w_qkv = (const float*)d_in[4];
  const float* w_o   = (const float*)d_in[5];

  float* out  = (float*)d_out;
  float* attn = out + (size_t)S_LEN * HID;

  char* ws = (char*)d_ws;
  f16* hs16   = (f16*)(ws + 0);          // reused later as AO
  f16* wq16   = (f16*)(ws + 12582912);   // reused later as Wo16
  f16* qkv16  = (f16*)(ws + 44040192);
  f16* Q16    = (f16*)(ws + 65011712);
  f16* K16    = (f16*)(ws + 77594624);
  f16* Vt16   = (f16*)(ws + 81788928);
  f16* AO16   = hs16;
  f16* Wo16   = wq16;

  k_cast4<<<6144, 256, 0, stream>>>(hs, hs16, (S_LEN * HID) / 4);
  k_cast4<<<15360, 256, 0, stream>>>(w_qkv, wq16, (OPSZ * HID) / 4);
  k_gemm_qkv<<<dim3(40, 16), 256, 0, stream>>>(hs16, wq16, qkv16);
  k_rope<<<32768, 256, 0, stream>>>(qkv16, cosd, sind, Q16, K16);
  k_vt<<<dim3(64, 4, 8), 256, 0, stream>>>(qkv16, Vt16);
  k_cast4<<<9216, 256, 0, stream>>>(w_o, Wo16, (HID * HID) / 4);
  // fused scores+softmax+PV (writes attn fp32 once, AO f16)
  k_attn<<<384, 256, 0, stream>>>(Q16, K16, Vt16, attn, AO16);
  k_gemm_out<<<dim3(24, 16), 256, 0, stream>>>(AO16, Wo16, out);
}

// Round 4
// 1056.435 us; speedup vs baseline: 1.1959x; 1.1959x over previous
//
#include <hip/hip_runtime.h>
#include <cstdint>
#include <cstddef>

#define S_LEN 2048
#define HID   3072
#define NH    24
#define NKV   8
#define HD    128
#define ROT   96
#define OPSZ  5120   // NH*HD + 2*NKV*HD
#define NREP  3      // NH/NKV
#define SCALING 0.08838834764831845f

typedef _Float16 f16;
typedef float f32x4 __attribute__((ext_vector_type(4)));
typedef _Float16 f16x8 __attribute__((ext_vector_type(8)));
typedef _Float16 f16x4 __attribute__((ext_vector_type(4)));

#define GLOBAL_AS __attribute__((address_space(1)))
#define LDS_AS    __attribute__((address_space(3)))

// ---------------- cast fp32 -> fp16 (4 elems/thread) ----------------
__global__ void k_cast4(const float* __restrict__ in, f16* __restrict__ out, int n4) {
  int i = blockIdx.x * blockDim.x + threadIdx.x;
  if (i >= n4) return;
  float4 v = reinterpret_cast<const float4*>(in)[i];
  f16x4 o = {(f16)v.x, (f16)v.y, (f16)v.z, (f16)v.w};
  reinterpret_cast<f16x4*>(out)[i] = o;
}

// ---------------- GEMM building blocks ----------------
__device__ __forceinline__ void stage_async(const f16* __restrict__ G, int ld, int m0, int k0,
                                            f16* __restrict__ Ls) {
  int t = threadIdx.x;
  int lane = t & 63, w = t >> 6;
#pragma unroll
  for (int j = 0; j < 2; ++j) {
    int rowBase = w * 16 + j * 64;            // wave-uniform
    int row = rowBase + (lane >> 2);
    int seg = lane & 3;
    const f16* gp = G + (size_t)(m0 + row) * ld + k0 + seg * 8;
    f16* lp = Ls + rowBase * 32;              // wave-uniform LDS base
    __builtin_amdgcn_global_load_lds((GLOBAL_AS const void*)gp, (LDS_AS void*)lp, 16, 0, 0);
  }
}

__device__ __forceinline__ void mma_tile(const f16* __restrict__ As, const f16* __restrict__ Bs,
                                         f32x4 acc[4][4], int wm, int wn, int lrow, int quad) {
  f16x8 a[4], b[4];
#pragma unroll
  for (int mi = 0; mi < 4; ++mi)
    a[mi] = *reinterpret_cast<const f16x8*>(As + (wm + mi * 16 + lrow) * 32 + quad * 8);
#pragma unroll
  for (int ni = 0; ni < 4; ++ni)
    b[ni] = *reinterpret_cast<const f16x8*>(Bs + (wn + ni * 16 + lrow) * 32 + quad * 8);
#pragma unroll
  for (int mi = 0; mi < 4; ++mi)
#pragma unroll
    for (int ni = 0; ni < 4; ++ni)
      acc[mi][ni] = __builtin_amdgcn_mfma_f32_16x16x32_f16(a[mi], b[ni], acc[mi][ni], 0, 0, 0);
}

// ---------------- QKV GEMM ----------------
__global__ __launch_bounds__(256) void k_gemm_qkv(const f16* __restrict__ A,
                                                  const f16* __restrict__ B,
                                                  f16* __restrict__ C) {
  int m0 = blockIdx.y * 128, n0 = blockIdx.x * 128;
  __shared__ __align__(16) f16 As[128 * 32];
  __shared__ __align__(16) f16 Bs[128 * 32];
  f32x4 acc[4][4] = {};
  int t = threadIdx.x, lane = t & 63, w = t >> 6;
  int wm = (w >> 1) * 64, wn = (w & 1) * 64, lrow = lane & 15, quad = lane >> 4;
  for (int kb = 0; kb < HID / 32; ++kb) {
    stage_async(A, HID, m0, kb * 32, As);
    stage_async(B, HID, n0, kb * 32, Bs);
    __syncthreads();
    mma_tile(As, Bs, acc, wm, wn, lrow, quad);
    __syncthreads();
  }
#pragma unroll
  for (int mi = 0; mi < 4; ++mi)
#pragma unroll
    for (int ni = 0; ni < 4; ++ni)
#pragma unroll
      for (int r = 0; r < 4; ++r) {
        int row = m0 + wm + mi * 16 + quad * 4 + r;
        int col = n0 + wn + ni * 16 + lrow;
        C[(size_t)row * OPSZ + col] = (f16)acc[mi][ni][r];
      }
}

// ---------------- out proj ----------------
__global__ __launch_bounds__(256) void k_gemm_out(const f16* __restrict__ A,
                                                  const f16* __restrict__ B,
                                                  float* __restrict__ C) {
  int m0 = blockIdx.y * 128, n0 = blockIdx.x * 128;
  __shared__ __align__(16) f16 As[128 * 32];
  __shared__ __align__(16) f16 Bs[128 * 32];
  f32x4 acc[4][4] = {};
  int t = threadIdx.x, lane = t & 63, w = t >> 6;
  int wm = (w >> 1) * 64, wn = (w & 1) * 64, lrow = lane & 15, quad = lane >> 4;
  for (int kb = 0; kb < HID / 32; ++kb) {
    stage_async(A, HID, m0, kb * 32, As);
    stage_async(B, HID, n0, kb * 32, Bs);
    __syncthreads();
    mma_tile(As, Bs, acc, wm, wn, lrow, quad);
    __syncthreads();
  }
#pragma unroll
  for (int mi = 0; mi < 4; ++mi)
#pragma unroll
    for (int ni = 0; ni < 4; ++ni)
#pragma unroll
      for (int r = 0; r < 4; ++r) {
        int row = m0 + wm + mi * 16 + quad * 4 + r;
        int col = n0 + wn + ni * 16 + lrow;
        C[(size_t)row * HID + col] = acc[mi][ni][r];
      }
}

// ---------------- RoPE on Q and K heads ----------------
__global__ void k_rope(const f16* __restrict__ qkv, const float* __restrict__ cosd,
                       const float* __restrict__ sind, f16* __restrict__ Q,
                       f16* __restrict__ Kc) {
  int idx = blockIdx.x * 256 + threadIdx.x;
  int d = idx & 127;
  int s = (idx >> 7) & (S_LEN - 1);
  int hh = idx >> 18;
  int srcCol = (hh < NH) ? hh * HD + d : HID + (hh - NH) * HD + d;
  float x = (float)qkv[(size_t)s * OPSZ + srcCol];
  float r;
  if (d < ROT) {
    float c = cosd[s * ROT + d], sn = sind[s * ROT + d];
    int pd = (d < 48) ? d + 48 : d - 48;
    float px = (float)qkv[(size_t)s * OPSZ + srcCol - d + pd];
    r = x * c + ((d < 48) ? -px : px) * sn;
  } else {
    r = x;
  }
  f16 o = (f16)r;
  if (hh < NH) Q[((size_t)hh * S_LEN + s) * HD + d] = o;
  else         Kc[((size_t)(hh - NH) * S_LEN + s) * HD + d] = o;
}

// ---------------- V transpose: Vt[8,128,2048] ----------------
__global__ void k_vt(const f16* __restrict__ qkv, f16* __restrict__ Vt) {
  __shared__ f16 tile[32][33];
  int s0 = blockIdx.x * 32, d0 = blockIdx.y * 32, kv = blockIdx.z;
  int tx = threadIdx.x & 31, ty = threadIdx.x >> 5;
#pragma unroll
  for (int i = 0; i < 4; ++i)
    tile[ty + i * 8][tx] = qkv[(size_t)(s0 + ty + i * 8) * OPSZ + 4096 + kv * HD + d0 + tx];
  __syncthreads();
#pragma unroll
  for (int i = 0; i < 4; ++i)
    Vt[((size_t)kv * HD + d0 + ty + i * 8) * S_LEN + s0 + tx] = tile[tx][ty + i * 8];
}

// ---------------- fused attention ----------------
// Swizzled stage: 16B-segment XOR swizzle applied on the GLOBAL source; LDS dest
// linear (global_load_lds requirement); read side XORs the same pattern.
template <int RB, int NR>
__device__ __forceinline__ void stage_swz(const f16* __restrict__ G, int ld,
                                          f16* __restrict__ Ls) {
  constexpr int RPI = 1024 / RB;          // rows per 1024B wave issue
  constexpr int SEGS = RB / 16;           // 16B segments per row
  constexpr int ISSUES = (NR * RB) / 4096;
  int t = threadIdx.x, lane = t & 63, w = t >> 6;
#pragma unroll
  for (int j = 0; j < ISSUES; ++j) {
    int rowBase = (w * ISSUES + j) * RPI;  // wave-uniform
    int row = rowBase + lane / SEGS;
    int gseg = (lane % SEGS) ^ (row & 7);
    const f16* gp = G + (size_t)row * ld + gseg * 8;
    f16* lp = Ls + rowBase * (RB / 2);     // wave-uniform LDS base
    __builtin_amdgcn_global_load_lds((GLOBAL_AS const void*)gp, (LDS_AS void*)lp, 16, 0, 0);
  }
}

// LDS slot ledger (4 x 16KB):  A = K buffer (pass-1 ping, pass-2 K).
//   S0 = pass-1 K pong, then V-slot rotation member. S1 = stats overlay, then rotation.
//   Pass-2 rotation: V slot = iv, P slot = (iv+1)%3, V-stage target = (iv+2)%3 —
//   pairwise distinct every iteration; iv advances by 2 mod 3.
//   Every slot has a __syncthreads between last-read and re-stage, and between
//   stage-issue and first-read (all barriers drain vmcnt+lgkmcnt).
__global__ __launch_bounds__(256, 2) void k_attn(const f16* __restrict__ Q,
                                                 const f16* __restrict__ Kc,
                                                 const f16* __restrict__ Vt,
                                                 float* __restrict__ attn,
                                                 f16* __restrict__ AO) {
  __shared__ __align__(16) f16 lds[4 * 8192];   // 64 KB
  f16* A_ = lds;

  // kv-head -> XCD clustering; heavy row-blocks dispatched first
  int bx = blockIdx.x;
  int kvh = bx & 7;
  int rr_ = bx >> 3;            // 0..47
  int qh = rr_ % 3;
  int bm = 15 - rr_ / 3;        // 15 (heavy) .. 0 (light)
  int h = kvh * NREP + qh;
  int m0 = bm * 128;
  int nt = 2 * (bm + 1);        // even always

  const f16* Qh = Q + (size_t)h * S_LEN * HD;
  const f16* Kh = Kc + (size_t)kvh * S_LEN * HD;
  const f16* Vh = Vt + (size_t)kvh * HD * S_LEN;
  float* attnH = attn + (size_t)h * S_LEN * S_LEN;

  int t = threadIdx.x, lane = t & 63, w = t >> 6;
  int wm = (w >> 1) * 64;       // row half (wave pair)
  int wn = (w & 1) * 32;        // col half within 64-wide KV tile
  int wn2 = (w & 1) * 64;       // col half within 128-wide PV output
  int lrow = lane & 15, quad = lane >> 4;

  // Q fragments in registers for the whole kernel
  f16x8 qf[4][4];
#pragma unroll
  for (int kq = 0; kq < 4; ++kq)
#pragma unroll
    for (int mi = 0; mi < 4; ++mi)
      qf[kq][mi] = *reinterpret_cast<const f16x8*>(
          Qh + (size_t)(m0 + wm + mi * 16 + lrow) * HD + kq * 32 + quad * 8);

  stage_swz<256, 64>(Kh, HD, A_);   // K(0) -> A

  // ---------------- pass 1: row stats (swapped QK^T: q-row = lane&15) ----------------
  float m1[4], l1[4];
#pragma unroll
  for (int mi = 0; mi < 4; ++mi) { m1[mi] = -1e30f; l1[mi] = 0.f; }

  for (int kb = 0; kb < nt; ++kb) {
    const char* cur = reinterpret_cast<const char*>((kb & 1) ? (lds + 8192) : A_);
    f16* nxt = (kb & 1) ? A_ : (lds + 8192);
    __syncthreads();             // K(kb) arrived (staged >=1 phase ago); nxt readers done
    if (kb + 1 < nt) stage_swz<256, 64>(Kh + (size_t)(kb + 1) * 64 * HD, HD, nxt);
    else             stage_swz<256, 64>(Kh, HD, nxt);   // K(0) for pass 2 (nxt==A, nt even)
    f32x4 sacc[2][4] = {};
    __builtin_amdgcn_s_setprio(1);
#pragma unroll
    for (int kq = 0; kq < 4; ++kq) {
      int kbyte = kq * 64 + quad * 16;
      f16x8 kf[2];
#pragma unroll
      for (int ni = 0; ni < 2; ++ni) {
        int rowb = wn + ni * 16 + lrow;
        kf[ni] = *reinterpret_cast<const f16x8*>(cur + rowb * 256 + (kbyte ^ ((rowb & 7) << 4)));
      }
#pragma unroll
      for (int ni = 0; ni < 2; ++ni)
#pragma unroll
        for (int mi = 0; mi < 4; ++mi)
          sacc[ni][mi] =
              __builtin_amdgcn_mfma_f32_16x16x32_f16(kf[ni], qf[kq][mi], sacc[ni][mi], 0, 0, 0);
    }
    __builtin_amdgcn_s_setprio(0);
    int tb = kb * 64 + wn + quad * 4;
#pragma unroll
    for (int mi = 0; mi < 4; ++mi) {
      int qg = m0 + wm + mi * 16 + lrow;
      float vals[8];
      float lm = -1e30f;
#pragma unroll
      for (int ni = 0; ni < 2; ++ni)
#pragma unroll
        for (int r2 = 0; r2 < 4; ++r2) {
          int tg = tb + ni * 16 + r2;
          float s = sacc[ni][mi][r2] * SCALING;
          s = (tg > qg) ? -1e30f : s;
          vals[ni * 4 + r2] = s;
          lm = fmaxf(lm, s);
        }
      lm = fmaxf(lm, __shfl_xor(lm, 16));
      lm = fmaxf(lm, __shfl_xor(lm, 32));
      float mold = m1[mi], mnew = fmaxf(mold, lm);
      float ps = 0.f;
#pragma unroll
      for (int j = 0; j < 8; ++j) ps += __expf(vals[j] - mnew);
      ps += __shfl_xor(ps, 16);
      ps += __shfl_xor(ps, 32);
      l1[mi] = l1[mi] * __expf(mold - mnew) + ps;
      m1[mi] = mnew;
    }
  }

  // ---------------- combine col-halves; prefetch V(0) ----------------
  float* sm = reinterpret_cast<float*>(lds + 16384);   // S1 overlay: [2][128] m
  float* sl = sm + 256;                                // [2][128] l
  __syncthreads();                       // pass-1 reads done; K(0) stage drained
  stage_swz<128, 128>(Vh, S_LEN, lds + 8192);          // V(0) -> slot0 (S0 free)
  if (quad == 0) {
#pragma unroll
    for (int mi = 0; mi < 4; ++mi) {
      int rL = wm + mi * 16 + lrow;
      sm[(w & 1) * 128 + rL] = m1[mi];
      sl[(w & 1) * 128 + rL] = l1[mi];
    }
  }
  __syncthreads();                       // stats visible; V(0) drained
  float m_f[4][4], il[4][4];
#pragma unroll
  for (int mi = 0; mi < 4; ++mi)
#pragma unroll
    for (int r2 = 0; r2 < 4; ++r2) {
      int rL = wm + mi * 16 + quad * 4 + r2;
      float ma = sm[rL], mb = sm[128 + rL];
      float la = sl[rL], lb = sl[128 + rL];
      float mm = fmaxf(ma, mb);
      float ll = la * __expf(ma - mm) + lb * __expf(mb - mm);
      m_f[mi][r2] = mm;
      il[mi][r2] = 1.0f / ll;
    }

  // ---------------- pass 2: P write + PV (2 barriers/iter; stages covered by PV) ----------------
  f32x4 oacc[4][4] = {};
  int iv = 0;   // V slot index: 0,2,1,0,...
  for (int kb = 0; kb < nt; ++kb) {
    __syncthreads();             // B1: K(kb)@A, V(kb)@slot iv ready; prev PV reads done
    f32x4 sacc[4][2] = {};
    __builtin_amdgcn_s_setprio(1);
#pragma unroll
    for (int kq = 0; kq < 4; ++kq) {
      int kbyte = kq * 64 + quad * 16;
      f16x8 b[2];
#pragma unroll
      for (int ni = 0; ni < 2; ++ni) {
        int rowb = wn + ni * 16 + lrow;
        b[ni] = *reinterpret_cast<const f16x8*>(
            reinterpret_cast<const char*>(A_) + rowb * 256 + (kbyte ^ ((rowb & 7) << 4)));
      }
#pragma unroll
      for (int mi = 0; mi < 4; ++mi)
#pragma unroll
        for (int ni = 0; ni < 2; ++ni)
          sacc[mi][ni] =
              __builtin_amdgcn_mfma_f32_16x16x32_f16(qf[kq][mi], b[ni], sacc[mi][ni], 0, 0, 0);
    }
    __builtin_amdgcn_s_setprio(0);
    // p: compute, LDS write (slot iv+1), fp32 global store
    char* Pslot = reinterpret_cast<char*>(lds) + (size_t)(1 + (iv + 1) % 3) * 16384;
    int n0 = kb * 64;
#pragma unroll
    for (int mi = 0; mi < 4; ++mi)
#pragma unroll
      for (int r2 = 0; r2 < 4; ++r2) {
        int rL = wm + mi * 16 + quad * 4 + r2;
        float mm = m_f[mi][r2], ilv = il[mi][r2];
#pragma unroll
        for (int ni = 0; ni < 2; ++ni) {
          int cL = wn + ni * 16 + lrow;
          int c = n0 + cL;
          float s = sacc[mi][ni][r2] * SCALING;
          if (c > m0 + rL) s = -1e30f;
          float p = __expf(s - mm) * ilv;
          attnH[(size_t)(m0 + rL) * S_LEN + c] = p;
          *reinterpret_cast<f16*>(Pslot + rL * 128 + ((cL * 2) ^ ((rL & 7) << 4))) = (f16)p;
        }
      }
    __syncthreads();             // B2: P visible; A/K consumed; P-stores drained
    if (kb + 1 < nt) {           // stages drain at next B1, covered by PV below
      stage_swz<256, 64>(Kh + (size_t)(kb + 1) * 64 * HD, HD, A_);
      stage_swz<128, 128>(Vh + (size_t)(kb + 1) * 64, S_LEN,
                          lds + (size_t)(1 + (iv + 2) % 3) * 8192);
    }
    const char* Vslot = reinterpret_cast<const char*>(lds) + (size_t)(1 + iv) * 16384;
    __builtin_amdgcn_s_setprio(1);
#pragma unroll
    for (int kq = 0; kq < 2; ++kq) {
      int kbyte = kq * 64 + quad * 16;
      f16x8 a[4], b[4];
#pragma unroll
      for (int mi = 0; mi < 4; ++mi) {
        int rowp = wm + mi * 16 + lrow;
        a[mi] = *reinterpret_cast<const f16x8*>(Pslot + rowp * 128 + (kbyte ^ ((rowp & 7) << 4)));
      }
#pragma unroll
      for (int ni = 0; ni < 4; ++ni) {
        int rowv = wn2 + ni * 16 + lrow;
        b[ni] = *reinterpret_cast<const f16x8*>(Vslot + rowv * 128 + (kbyte ^ ((rowv & 7) << 4)));
      }
#pragma unroll
      for (int mi = 0; mi < 4; ++mi)
#pragma unroll
        for (int ni = 0; ni < 4; ++ni)
          oacc[mi][ni] =
              __builtin_amdgcn_mfma_f32_16x16x32_f16(a[mi], b[ni], oacc[mi][ni], 0, 0, 0);
    }
    __builtin_amdgcn_s_setprio(0);
    iv = (iv + 2) % 3;
  }

  // AO epilogue
#pragma unroll
  for (int mi = 0; mi < 4; ++mi)
#pragma unroll
    for (int ni = 0; ni < 4; ++ni)
#pragma unroll
      for (int r = 0; r < 4; ++r) {
        int row = m0 + wm + mi * 16 + quad * 4 + r;
        int col = wn2 + ni * 16 + lrow;
        AO[(size_t)row * HID + h * HD + col] = (f16)oacc[mi][ni][r];
      }

  // zero-fill fully masked cols >= (bm+1)*128
  float4 z = {0.f, 0.f, 0.f, 0.f};
  for (int zt = bm + 1; zt < 16; ++zt) {
    float* outp = attnH + (size_t)m0 * S_LEN + zt * 128;
#pragma unroll
    for (int j = 0; j < 16; ++j) {
      int lin = t + 256 * j;
      int rowz = lin >> 5, seg = lin & 31;
      reinterpret_cast<float4*>(outp + (size_t)rowz * S_LEN)[seg] = z;
    }
  }
}

// ---------------- launch ----------------
extern "C" void kernel_launch(void* const* d_in, const int* in_sizes, int n_in,
                              void* d_out, int out_size, void* d_ws, size_t ws_size,
                              hipStream_t stream) {
  const float* hs    = (const float*)d_in[0];
  const float* cosd  = (const float*)d_in[1];
  const float* sind  = (const float*)d_in[2];
  // d_in[3] = attention_mask (causal by construction; unused)
  const float* w_qkv = (const float*)d_in[4];
  const float* w_o   = (const float*)d_in[5];

  float* out  = (float*)d_out;
  float* attn = out + (size_t)S_LEN * HID;

  char* ws = (char*)d_ws;
  f16* hs16   = (f16*)(ws + 0);          // reused later as AO
  f16* wq16   = (f16*)(ws + 12582912);   // reused later as Wo16
  f16* qkv16  = (f16*)(ws + 44040192);
  f16* Q16    = (f16*)(ws + 65011712);
  f16* K16    = (f16*)(ws + 77594624);
  f16* Vt16   = (f16*)(ws + 81788928);
  f16* AO16   = hs16;
  f16* Wo16   = wq16;

  k_cast4<<<6144, 256, 0, stream>>>(hs, hs16, (S_LEN * HID) / 4);
  k_cast4<<<15360, 256, 0, stream>>>(w_qkv, wq16, (OPSZ * HID) / 4);
  k_gemm_qkv<<<dim3(40, 16), 256, 0, stream>>>(hs16, wq16, qkv16);
  k_rope<<<32768, 256, 0, stream>>>(qkv16, cosd, sind, Q16, K16);
  k_vt<<<dim3(64, 4, 8), 256, 0, stream>>>(qkv16, Vt16);
  k_cast4<<<9216, 256, 0, stream>>>(w_o, Wo16, (HID * HID) / 4);
  // fused scores+softmax+PV (writes attn fp32 once, AO f16)
  k_attn<<<384, 256, 0, stream>>>(Q16, K16, Vt16, attn, AO16);
  k_gemm_out<<<dim3(24, 16), 256, 0, stream>>>(AO16, Wo16, out);
}

// Round 6
// 1014.192 us; speedup vs baseline: 1.2457x; 1.0417x over previous
//
#include <hip/hip_runtime.h>
#include <cstdint>
#include <cstddef>

#define S_LEN 2048
#define HID   3072
#define NH    24
#define NKV   8
#define HD    128
#define ROT   96
#define OPSZ  5120   // NH*HD + 2*NKV*HD
#define NREP  3      // NH/NKV
#define SCALING 0.08838834764831845f

typedef _Float16 f16;
typedef float f32x4 __attribute__((ext_vector_type(4)));
typedef _Float16 f16x8 __attribute__((ext_vector_type(8)));
typedef _Float16 f16x4 __attribute__((ext_vector_type(4)));

#define GLOBAL_AS __attribute__((address_space(1)))
#define LDS_AS    __attribute__((address_space(3)))

// ---------------- cast fp32 -> fp16 (4 elems/thread) ----------------
__global__ void k_cast4(const float* __restrict__ in, f16* __restrict__ out, int n4) {
  int i = blockIdx.x * blockDim.x + threadIdx.x;
  if (i >= n4) return;
  float4 v = reinterpret_cast<const float4*>(in)[i];
  f16x4 o = {(f16)v.x, (f16)v.y, (f16)v.z, (f16)v.w};
  reinterpret_cast<f16x4*>(out)[i] = o;
}

// ---------------- GEMM building blocks ----------------
__device__ __forceinline__ void stage_async(const f16* __restrict__ G, int ld, int m0, int k0,
                                            f16* __restrict__ Ls) {
  int t = threadIdx.x;
  int lane = t & 63, w = t >> 6;
#pragma unroll
  for (int j = 0; j < 2; ++j) {
    int rowBase = w * 16 + j * 64;            // wave-uniform
    int row = rowBase + (lane >> 2);
    int seg = lane & 3;
    const f16* gp = G + (size_t)(m0 + row) * ld + k0 + seg * 8;
    f16* lp = Ls + rowBase * 32;              // wave-uniform LDS base
    __builtin_amdgcn_global_load_lds((GLOBAL_AS const void*)gp, (LDS_AS void*)lp, 16, 0, 0);
  }
}

__device__ __forceinline__ void mma_tile(const f16* __restrict__ As, const f16* __restrict__ Bs,
                                         f32x4 acc[4][4], int wm, int wn, int lrow, int quad) {
  f16x8 a[4], b[4];
#pragma unroll
  for (int mi = 0; mi < 4; ++mi)
    a[mi] = *reinterpret_cast<const f16x8*>(As + (wm + mi * 16 + lrow) * 32 + quad * 8);
#pragma unroll
  for (int ni = 0; ni < 4; ++ni)
    b[ni] = *reinterpret_cast<const f16x8*>(Bs + (wn + ni * 16 + lrow) * 32 + quad * 8);
#pragma unroll
  for (int mi = 0; mi < 4; ++mi)
#pragma unroll
    for (int ni = 0; ni < 4; ++ni)
      acc[mi][ni] = __builtin_amdgcn_mfma_f32_16x16x32_f16(a[mi], b[ni], acc[mi][ni], 0, 0, 0);
}

// ---------------- QKV GEMM (XCD-swizzled 1-D grid: 640 = 8 xcd * 40 n * 2 m) ----------------
__global__ __launch_bounds__(256) void k_gemm_qkv(const f16* __restrict__ A,
                                                  const f16* __restrict__ B,
                                                  f16* __restrict__ C) {
  int bx = blockIdx.x;
  int xcd = bx & 7, i = bx >> 3;               // i: 0..79
  int n0 = (i >> 1) * 128;                     // n-major within XCD
  int m0 = (xcd * 2 + (i & 1)) * 128;          // 2 m-blocks pinned per XCD
  __shared__ __align__(16) f16 As[128 * 32];
  __shared__ __align__(16) f16 Bs[128 * 32];
  f32x4 acc[4][4] = {};
  int t = threadIdx.x, lane = t & 63, w = t >> 6;
  int wm = (w >> 1) * 64, wn = (w & 1) * 64, lrow = lane & 15, quad = lane >> 4;
  for (int kb = 0; kb < HID / 32; ++kb) {
    stage_async(A, HID, m0, kb * 32, As);
    stage_async(B, HID, n0, kb * 32, Bs);
    __syncthreads();
    mma_tile(As, Bs, acc, wm, wn, lrow, quad);
    __syncthreads();
  }
#pragma unroll
  for (int mi = 0; mi < 4; ++mi)
#pragma unroll
    for (int ni = 0; ni < 4; ++ni)
#pragma unroll
      for (int r = 0; r < 4; ++r) {
        int row = m0 + wm + mi * 16 + quad * 4 + r;
        int col = n0 + wn + ni * 16 + lrow;
        C[(size_t)row * OPSZ + col] = (f16)acc[mi][ni][r];
      }
}

// ---------------- out proj (XCD-swizzled 1-D grid: 384 = 8 xcd * 24 n * 2 m) ----------------
__global__ __launch_bounds__(256) void k_gemm_out(const f16* __restrict__ A,
                                                  const f16* __restrict__ B,
                                                  float* __restrict__ C) {
  int bx = blockIdx.x;
  int xcd = bx & 7, i = bx >> 3;               // i: 0..47
  int n0 = (i >> 1) * 128;
  int m0 = (xcd * 2 + (i & 1)) * 128;
  __shared__ __align__(16) f16 As[128 * 32];
  __shared__ __align__(16) f16 Bs[128 * 32];
  f32x4 acc[4][4] = {};
  int t = threadIdx.x, lane = t & 63, w = t >> 6;
  int wm = (w >> 1) * 64, wn = (w & 1) * 64, lrow = lane & 15, quad = lane >> 4;
  for (int kb = 0; kb < HID / 32; ++kb) {
    stage_async(A, HID, m0, kb * 32, As);
    stage_async(B, HID, n0, kb * 32, Bs);
    __syncthreads();
    mma_tile(As, Bs, acc, wm, wn, lrow, quad);
    __syncthreads();
  }
#pragma unroll
  for (int mi = 0; mi < 4; ++mi)
#pragma unroll
    for (int ni = 0; ni < 4; ++ni)
#pragma unroll
      for (int r = 0; r < 4; ++r) {
        int row = m0 + wm + mi * 16 + quad * 4 + r;
        int col = n0 + wn + ni * 16 + lrow;
        C[(size_t)row * HID + col] = acc[mi][ni][r];
      }
}

// ---------------- RoPE on Q and K heads ----------------
__global__ void k_rope(const f16* __restrict__ qkv, const float* __restrict__ cosd,
                       const float* __restrict__ sind, f16* __restrict__ Q,
                       f16* __restrict__ Kc) {
  int idx = blockIdx.x * 256 + threadIdx.x;
  int d = idx & 127;
  int s = (idx >> 7) & (S_LEN - 1);
  int hh = idx >> 18;
  int srcCol = (hh < NH) ? hh * HD + d : HID + (hh - NH) * HD + d;
  float x = (float)qkv[(size_t)s * OPSZ + srcCol];
  float r;
  if (d < ROT) {
    float c = cosd[s * ROT + d], sn = sind[s * ROT + d];
    int pd = (d < 48) ? d + 48 : d - 48;
    float px = (float)qkv[(size_t)s * OPSZ + srcCol - d + pd];
    r = x * c + ((d < 48) ? -px : px) * sn;
  } else {
    r = x;
  }
  f16 o = (f16)r;
  if (hh < NH) Q[((size_t)hh * S_LEN + s) * HD + d] = o;
  else         Kc[((size_t)(hh - NH) * S_LEN + s) * HD + d] = o;
}

// ---------------- V transpose: Vt[8,128,2048] ----------------
__global__ void k_vt(const f16* __restrict__ qkv, f16* __restrict__ Vt) {
  __shared__ f16 tile[32][33];
  int s0 = blockIdx.x * 32, d0 = blockIdx.y * 32, kv = blockIdx.z;
  int tx = threadIdx.x & 31, ty = threadIdx.x >> 5;
#pragma unroll
  for (int i = 0; i < 4; ++i)
    tile[ty + i * 8][tx] = qkv[(size_t)(s0 + ty + i * 8) * OPSZ + 4096 + kv * HD + d0 + tx];
  __syncthreads();
#pragma unroll
  for (int i = 0; i < 4; ++i)
    Vt[((size_t)kv * HD + d0 + ty + i * 8) * S_LEN + s0 + tx] = tile[tx][ty + i * 8];
}

// ---------------- fused attention pieces ----------------
// Swizzled stage: 16B-segment XOR swizzle applied on the GLOBAL source; LDS dest
// linear (global_load_lds requirement); read side XORs the same pattern.
template <int RB, int NR, int NTHR>
__device__ __forceinline__ void stage_swz(const f16* __restrict__ G, int ld,
                                          f16* __restrict__ Ls) {
  constexpr int RPI = 1024 / RB;          // rows per 1024B wave issue
  constexpr int SEGS = RB / 16;           // 16B segments per row
  constexpr int ISSUES = (NR * RB) / ((NTHR / 64) * 1024);
  int t = threadIdx.x, lane = t & 63, w = t >> 6;
#pragma unroll
  for (int j = 0; j < ISSUES; ++j) {
    int rowBase = (w * ISSUES + j) * RPI;  // wave-uniform
    int row = rowBase + lane / SEGS;
    int gseg = (lane % SEGS) ^ (row & 7);
    const f16* gp = G + (size_t)row * ld + gseg * 8;
    f16* lp = Ls + rowBase * (RB / 2);     // wave-uniform LDS base
    __builtin_amdgcn_global_load_lds((GLOBAL_AS const void*)gp, (LDS_AS void*)lp, 16, 0, 0);
  }
}

// Pass-1 stats, KV-chunked x4 for parallelism. Grid 1536 (8 kvh x 4 chunk x 3 qh x 16 bm),
// 512 threads. Block (h,bm,c) covers KV tiles [c*8, min(c*8+8, 2(bm+1))).
// Output per q-row partial (m, l) -> stats[((h*16+bm)*4+c)*128 + row].
__global__ __launch_bounds__(512) void k_stats(const f16* __restrict__ Q,
                                               const f16* __restrict__ Kc,
                                               float2* __restrict__ stats) {
  __shared__ __align__(16) f16 Ks2[2][8192];   // 2 x 16KB K double buffer
  __shared__ float smx[4 * 128], slx[4 * 128];
  int bx = blockIdx.x;
  int kvh = bx & 7;
  int rr = bx >> 3;            // 0..191
  int c = rr & 3;
  int rr2 = rr >> 2;           // 0..47
  int qh = rr2 % 3;
  int bm = 15 - rr2 / 3;       // heavy-first
  if (c * 4 > bm) return;      // chunk fully above diagonal: inactive
  int h = kvh * NREP + qh;
  int m0 = bm * 128;
  int t0 = c * 8;
  int nt = 2 * (bm + 1);
  int t1 = (t0 + 8 < nt) ? t0 + 8 : nt;

  const f16* Qh = Q + (size_t)h * S_LEN * HD;
  const f16* Kh = Kc + (size_t)kvh * S_LEN * HD;
  int t = threadIdx.x, lane = t & 63, w = t >> 6;
  int wm = (w >> 2) * 64;      // q row-half
  int wn = (w & 3) * 16;       // t col-group (16 wide)
  int lrow = lane & 15, quad = lane >> 4;

  f16x8 qf[4][4];
#pragma unroll
  for (int kq = 0; kq < 4; ++kq)
#pragma unroll
    for (int mi = 0; mi < 4; ++mi)
      qf[kq][mi] = *reinterpret_cast<const f16x8*>(
          Qh + (size_t)(m0 + wm + mi * 16 + lrow) * HD + kq * 32 + quad * 8);

  stage_swz<256, 64, 512>(Kh + (size_t)t0 * 64 * HD, HD, Ks2[0]);

  float m1[4], l1[4];
#pragma unroll
  for (int mi = 0; mi < 4; ++mi) { m1[mi] = -1e30f; l1[mi] = 0.f; }

  for (int kt = t0; kt < t1; ++kt) {
    const char* cur = reinterpret_cast<const char*>(Ks2[(kt - t0) & 1]);
    __syncthreads();           // K(kt) arrived; pong readers done
    if (kt + 1 < t1)
      stage_swz<256, 64, 512>(Kh + (size_t)(kt + 1) * 64 * HD, HD, Ks2[(kt - t0 + 1) & 1]);
    f32x4 sacc[4] = {};
    __builtin_amdgcn_s_setprio(1);
#pragma unroll
    for (int kq = 0; kq < 4; ++kq) {
      int rowb = wn + lrow;
      f16x8 kf = *reinterpret_cast<const f16x8*>(
          cur + rowb * 256 + ((kq * 64 + quad * 16) ^ ((rowb & 7) << 4)));
#pragma unroll
      for (int mi = 0; mi < 4; ++mi)
        sacc[mi] = __builtin_amdgcn_mfma_f32_16x16x32_f16(kf, qf[kq][mi], sacc[mi], 0, 0, 0);
    }
    __builtin_amdgcn_s_setprio(0);
#pragma unroll
    for (int mi = 0; mi < 4; ++mi) {
      int qg = m0 + wm + mi * 16 + lrow;   // lane's q-row (D col = lane&15)
      float vals[4], lm = -1e30f;
#pragma unroll
      for (int r = 0; r < 4; ++r) {
        int tg = kt * 64 + wn + quad * 4 + r;
        float s = sacc[mi][r] * SCALING;
        s = (tg > qg) ? -1e30f : s;
        vals[r] = s;
        lm = fmaxf(lm, s);
      }
      lm = fmaxf(lm, __shfl_xor(lm, 16));
      lm = fmaxf(lm, __shfl_xor(lm, 32));
      float mold = m1[mi], mnew = fmaxf(mold, lm);
      float ps = 0.f;
#pragma unroll
      for (int r = 0; r < 4; ++r) ps += __expf(vals[r] - mnew);
      ps += __shfl_xor(ps, 16);
      ps += __shfl_xor(ps, 32);
      l1[mi] = l1[mi] * __expf(mold - mnew) + ps;
      m1[mi] = mnew;
    }
  }

  if (quad == 0) {
#pragma unroll
    for (int mi = 0; mi < 4; ++mi) {
      smx[(w & 3) * 128 + wm + mi * 16 + lrow] = m1[mi];
      slx[(w & 3) * 128 + wm + mi * 16 + lrow] = l1[mi];
    }
  }
  __syncthreads();
  if (t < 128) {
    float mg = smx[t];
#pragma unroll
    for (int g = 1; g < 4; ++g) mg = fmaxf(mg, smx[g * 128 + t]);
    float la = 0.f;
#pragma unroll
    for (int g = 0; g < 4; ++g) la += slx[g * 128 + t] * __expf(smx[g * 128 + t] - mg);
    float2 o; o.x = mg; o.y = la;
    stats[((size_t)(h * 16 + bm) * 4 + c) * 128 + t] = o;
  }
}

// Pass-2: combine chunk stats, then per KV tile: QK^T, P=exp(S-m)/l (nontemporal
// fp32 store + swizzled f16 LDS), PV MFMA. LDS slot ledger identical to round 4:
// A = K; rotation slots 0..2 at lds+(1+s)*8192: V slot=iv, P slot=(iv+1)%3,
// V-stage target=(iv+2)%3; iv += 2 mod 3. Every slot: barrier between last-read
// and re-stage, and between stage-issue and first-read.
__global__ __launch_bounds__(256, 2) void k_pv2(const f16* __restrict__ Q,
                                                const f16* __restrict__ Kc,
                                                const f16* __restrict__ Vt,
                                                const float2* __restrict__ stats,
                                                float* __restrict__ attn,
                                                f16* __restrict__ AO) {
  __shared__ __align__(16) f16 lds[4 * 8192];   // 64 KB
  f16* A_ = lds;

  int bx = blockIdx.x;
  int kvh = bx & 7;
  int rr_ = bx >> 3;            // 0..47
  int qh = rr_ % 3;
  int bm = 15 - rr_ / 3;        // heavy-first
  int h = kvh * NREP + qh;
  int m0 = bm * 128;
  int nt = 2 * (bm + 1);

  const f16* Qh = Q + (size_t)h * S_LEN * HD;
  const f16* Kh = Kc + (size_t)kvh * S_LEN * HD;
  const f16* Vh = Vt + (size_t)kvh * HD * S_LEN;
  float* attnH = attn + (size_t)h * S_LEN * S_LEN;

  int t = threadIdx.x, lane = t & 63, w = t >> 6;
  int wm = (w >> 1) * 64;       // row half (wave pair)
  int wn = (w & 1) * 32;        // col half within 64-wide KV tile
  int wn2 = (w & 1) * 64;       // col half within 128-wide PV output
  int lrow = lane & 15, quad = lane >> 4;

  // issue first stages immediately; latency hides under prologue ALU
  stage_swz<256, 64, 256>(Kh, HD, A_);                 // K(0) -> A
  stage_swz<128, 128, 256>(Vh, S_LEN, lds + 8192);     // V(0) -> slot 0

  f16x8 qf[4][4];
#pragma unroll
  for (int kq = 0; kq < 4; ++kq)
#pragma unroll
    for (int mi = 0; mi < 4; ++mi)
      qf[kq][mi] = *reinterpret_cast<const f16x8*>(
          Qh + (size_t)(m0 + wm + mi * 16 + lrow) * HD + kq * 32 + quad * 8);

  // combine chunk partials -> final (m, 1/l) per owned row
  int nc = bm / 4 + 1;
  const float2* st = stats + (size_t)(h * 16 + bm) * 4 * 128;
  float m_f[4][4], il[4][4];
#pragma unroll
  for (int mi = 0; mi < 4; ++mi)
#pragma unroll
    for (int r2 = 0; r2 < 4; ++r2) {
      int rL = wm + mi * 16 + quad * 4 + r2;
      float mm = -1e30f, ll = 0.f;
      for (int c2 = 0; c2 < nc; ++c2) {
        float2 p = st[c2 * 128 + rL];
        float mn = fmaxf(mm, p.x);
        ll = ll * __expf(mm - mn) + p.y * __expf(p.x - mn);
        mm = mn;
      }
      m_f[mi][r2] = mm;
      il[mi][r2] = 1.0f / ll;
    }

  f32x4 oacc[4][4] = {};
  int iv = 0;   // V slot index: 0,2,1,0,...
  for (int kb = 0; kb < nt; ++kb) {
    __syncthreads();             // B1: K(kb)@A, V(kb)@slot iv ready; prev PV reads done
    f32x4 sacc[4][2] = {};
    __builtin_amdgcn_s_setprio(1);
#pragma unroll
    for (int kq = 0; kq < 4; ++kq) {
      int kbyte = kq * 64 + quad * 16;
      f16x8 b[2];
#pragma unroll
      for (int ni = 0; ni < 2; ++ni) {
        int rowb = wn + ni * 16 + lrow;
        b[ni] = *reinterpret_cast<const f16x8*>(
            reinterpret_cast<const char*>(A_) + rowb * 256 + (kbyte ^ ((rowb & 7) << 4)));
      }
#pragma unroll
      for (int mi = 0; mi < 4; ++mi)
#pragma unroll
        for (int ni = 0; ni < 2; ++ni)
          sacc[mi][ni] =
              __builtin_amdgcn_mfma_f32_16x16x32_f16(qf[kq][mi], b[ni], sacc[mi][ni], 0, 0, 0);
    }
    __builtin_amdgcn_s_setprio(0);
    // P: nontemporal fp32 store (don't evict K/V from L2) + swizzled f16 LDS write
    char* Pslot = reinterpret_cast<char*>(lds) + (size_t)(1 + (iv + 1) % 3) * 16384;
    int n0 = kb * 64;
#pragma unroll
    for (int mi = 0; mi < 4; ++mi)
#pragma unroll
      for (int r2 = 0; r2 < 4; ++r2) {
        int rL = wm + mi * 16 + quad * 4 + r2;
        float mm = m_f[mi][r2], ilv = il[mi][r2];
#pragma unroll
        for (int ni = 0; ni < 2; ++ni) {
          int cL = wn + ni * 16 + lrow;
          int c = n0 + cL;
          float s = sacc[mi][ni][r2] * SCALING;
          if (c > m0 + rL) s = -1e30f;
          float p = __expf(s - mm) * ilv;
          __builtin_nontemporal_store(p, attnH + (size_t)(m0 + rL) * S_LEN + c);
          *reinterpret_cast<f16*>(Pslot + rL * 128 + ((cL * 2) ^ ((rL & 7) << 4))) = (f16)p;
        }
      }
    __syncthreads();             // B2: P visible; A/K consumed; P-stores drained
    if (kb + 1 < nt) {           // stages drain at next B1, covered by PV below
      stage_swz<256, 64, 256>(Kh + (size_t)(kb + 1) * 64 * HD, HD, A_);
      stage_swz<128, 128, 256>(Vh + (size_t)(kb + 1) * 64, S_LEN,
                               lds + (size_t)(1 + (iv + 2) % 3) * 8192);
    }
    const char* Vslot = reinterpret_cast<const char*>(lds) + (size_t)(1 + iv) * 16384;
    __builtin_amdgcn_s_setprio(1);
#pragma unroll
    for (int kq = 0; kq < 2; ++kq) {
      int kbyte = kq * 64 + quad * 16;
      f16x8 a[4], b[4];
#pragma unroll
      for (int mi = 0; mi < 4; ++mi) {
        int rowp = wm + mi * 16 + lrow;
        a[mi] = *reinterpret_cast<const f16x8*>(Pslot + rowp * 128 + (kbyte ^ ((rowp & 7) << 4)));
      }
#pragma unroll
      for (int ni = 0; ni < 4; ++ni) {
        int rowv = wn2 + ni * 16 + lrow;
        b[ni] = *reinterpret_cast<const f16x8*>(Vslot + rowv * 128 + (kbyte ^ ((rowv & 7) << 4)));
      }
#pragma unroll
      for (int mi = 0; mi < 4; ++mi)
#pragma unroll
        for (int ni = 0; ni < 4; ++ni)
          oacc[mi][ni] =
              __builtin_amdgcn_mfma_f32_16x16x32_f16(a[mi], b[ni], oacc[mi][ni], 0, 0, 0);
    }
    __builtin_amdgcn_s_setprio(0);
    iv = (iv + 2) % 3;
  }

  // AO epilogue (re-read by gemm_out: keep cached)
#pragma unroll
  for (int mi = 0; mi < 4; ++mi)
#pragma unroll
    for (int ni = 0; ni < 4; ++ni)
#pragma unroll
      for (int r = 0; r < 4; ++r) {
        int row = m0 + wm + mi * 16 + quad * 4 + r;
        int col = wn2 + ni * 16 + lrow;
        AO[(size_t)row * HID + h * HD + col] = (f16)oacc[mi][ni][r];
      }

  // zero-fill fully masked cols >= (bm+1)*128 (nontemporal, clang ext-vector f32x4)
  f32x4 z = {0.f, 0.f, 0.f, 0.f};
  for (int zt = bm + 1; zt < 16; ++zt) {
    float* outp = attnH + (size_t)m0 * S_LEN + zt * 128;
#pragma unroll
    for (int j = 0; j < 16; ++j) {
      int lin = t + 256 * j;
      int rowz = lin >> 5, seg = lin & 31;
      __builtin_nontemporal_store(z, reinterpret_cast<f32x4*>(outp + (size_t)rowz * S_LEN) + seg);
    }
  }
}

// ---------------- launch ----------------
extern "C" void kernel_launch(void* const* d_in, const int* in_sizes, int n_in,
                              void* d_out, int out_size, void* d_ws, size_t ws_size,
                              hipStream_t stream) {
  const float* hs    = (const float*)d_in[0];
  const float* cosd  = (const float*)d_in[1];
  const float* sind  = (const float*)d_in[2];
  // d_in[3] = attention_mask (causal by construction; unused)
  const float* w_qkv = (const float*)d_in[4];
  const float* w_o   = (const float*)d_in[5];

  float* out  = (float*)d_out;
  float* attn = out + (size_t)S_LEN * HID;

  char* ws = (char*)d_ws;
  f16* hs16   = (f16*)(ws + 0);          // reused later as AO
  f16* wq16   = (f16*)(ws + 12582912);   // reused later as Wo16 (+ stats tail)
  f16* qkv16  = (f16*)(ws + 44040192);
  f16* Q16    = (f16*)(ws + 65011712);
  f16* K16    = (f16*)(ws + 77594624);
  f16* Vt16   = (f16*)(ws + 81788928);
  f16* AO16   = hs16;
  f16* Wo16   = wq16;
  // stats: 24*16*4*128 float2 = 1.5 MB; lives in wq16 tail after Wo16 (18,874,368 B).
  // wq16 (QKV weight) is dead after k_gemm_qkv; no overlap with Wo16.
  float2* stats = (float2*)(ws + 12582912 + 18874368);

  k_cast4<<<6144, 256, 0, stream>>>(hs, hs16, (S_LEN * HID) / 4);
  k_cast4<<<15360, 256, 0, stream>>>(w_qkv, wq16, (OPSZ * HID) / 4);
  k_gemm_qkv<<<640, 256, 0, stream>>>(hs16, wq16, qkv16);
  k_rope<<<32768, 256, 0, stream>>>(qkv16, cosd, sind, Q16, K16);
  k_vt<<<dim3(64, 4, 8), 256, 0, stream>>>(qkv16, Vt16);
  k_cast4<<<9216, 256, 0, stream>>>(w_o, Wo16, (HID * HID) / 4);
  // attention: chunked stats, then fused P-write + PV
  k_stats<<<1536, 512, 0, stream>>>(Q16, K16, stats);
  k_pv2<<<384, 256, 0, stream>>>(Q16, K16, Vt16, stats, attn, AO16);
  k_gemm_out<<<384, 256, 0, stream>>>(AO16, Wo16, out);
}

// Round 7
// 986.067 us; speedup vs baseline: 1.2813x; 1.0285x over previous
//
#include <hip/hip_runtime.h>
#include <cstdint>
#include <cstddef>

#define S_LEN 2048
#define HID   3072
#define NH    24
#define NKV   8
#define HD    128
#define ROT   96
#define OPSZ  5120   // NH*HD + 2*NKV*HD
#define NREP  3      // NH/NKV
#define SCALING 0.08838834764831845f

typedef _Float16 f16;
typedef float f32x4 __attribute__((ext_vector_type(4)));
typedef _Float16 f16x8 __attribute__((ext_vector_type(8)));
typedef _Float16 f16x4 __attribute__((ext_vector_type(4)));

#define GLOBAL_AS __attribute__((address_space(1)))
#define LDS_AS    __attribute__((address_space(3)))

// ---------------- cast fp32 -> fp16 (4 elems/thread) ----------------
__global__ void k_cast4(const float* __restrict__ in, f16* __restrict__ out, int n4) {
  int i = blockIdx.x * blockDim.x + threadIdx.x;
  if (i >= n4) return;
  float4 v = reinterpret_cast<const float4*>(in)[i];
  f16x4 o = {(f16)v.x, (f16)v.y, (f16)v.z, (f16)v.w};
  reinterpret_cast<f16x4*>(out)[i] = o;
}

// ---------------- GEMM building blocks ----------------
__device__ __forceinline__ void stage_async(const f16* __restrict__ G, int ld, int m0, int k0,
                                            f16* __restrict__ Ls) {
  int t = threadIdx.x;
  int lane = t & 63, w = t >> 6;
#pragma unroll
  for (int j = 0; j < 2; ++j) {
    int rowBase = w * 16 + j * 64;            // wave-uniform
    int row = rowBase + (lane >> 2);
    int seg = lane & 3;
    const f16* gp = G + (size_t)(m0 + row) * ld + k0 + seg * 8;
    f16* lp = Ls + rowBase * 32;              // wave-uniform LDS base
    __builtin_amdgcn_global_load_lds((GLOBAL_AS const void*)gp, (LDS_AS void*)lp, 16, 0, 0);
  }
}

__device__ __forceinline__ void mma_tile(const f16* __restrict__ As, const f16* __restrict__ Bs,
                                         f32x4 acc[4][4], int wm, int wn, int lrow, int quad) {
  f16x8 a[4], b[4];
#pragma unroll
  for (int mi = 0; mi < 4; ++mi)
    a[mi] = *reinterpret_cast<const f16x8*>(As + (wm + mi * 16 + lrow) * 32 + quad * 8);
#pragma unroll
  for (int ni = 0; ni < 4; ++ni)
    b[ni] = *reinterpret_cast<const f16x8*>(Bs + (wn + ni * 16 + lrow) * 32 + quad * 8);
#pragma unroll
  for (int mi = 0; mi < 4; ++mi)
#pragma unroll
    for (int ni = 0; ni < 4; ++ni)
      acc[mi][ni] = __builtin_amdgcn_mfma_f32_16x16x32_f16(a[mi], b[ni], acc[mi][ni], 0, 0, 0);
}

// ---------------- QKV GEMM (XCD-swizzled 1-D grid: 640 = 8 xcd * 40 n * 2 m) ----------------
__global__ __launch_bounds__(256) void k_gemm_qkv(const f16* __restrict__ A,
                                                  const f16* __restrict__ B,
                                                  f16* __restrict__ C) {
  int bx = blockIdx.x;
  int xcd = bx & 7, i = bx >> 3;               // i: 0..79
  int n0 = (i >> 1) * 128;                     // n-major within XCD
  int m0 = (xcd * 2 + (i & 1)) * 128;          // 2 m-blocks pinned per XCD
  __shared__ __align__(16) f16 As[128 * 32];
  __shared__ __align__(16) f16 Bs[128 * 32];
  f32x4 acc[4][4] = {};
  int t = threadIdx.x, lane = t & 63, w = t >> 6;
  int wm = (w >> 1) * 64, wn = (w & 1) * 64, lrow = lane & 15, quad = lane >> 4;
  for (int kb = 0; kb < HID / 32; ++kb) {
    stage_async(A, HID, m0, kb * 32, As);
    stage_async(B, HID, n0, kb * 32, Bs);
    __syncthreads();
    mma_tile(As, Bs, acc, wm, wn, lrow, quad);
    __syncthreads();
  }
#pragma unroll
  for (int mi = 0; mi < 4; ++mi)
#pragma unroll
    for (int ni = 0; ni < 4; ++ni)
#pragma unroll
      for (int r = 0; r < 4; ++r) {
        int row = m0 + wm + mi * 16 + quad * 4 + r;
        int col = n0 + wn + ni * 16 + lrow;
        C[(size_t)row * OPSZ + col] = (f16)acc[mi][ni][r];
      }
}

// ---------------- out proj (XCD-swizzled 1-D grid: 384 = 8 xcd * 24 n * 2 m) ----------------
__global__ __launch_bounds__(256) void k_gemm_out(const f16* __restrict__ A,
                                                  const f16* __restrict__ B,
                                                  float* __restrict__ C) {
  int bx = blockIdx.x;
  int xcd = bx & 7, i = bx >> 3;               // i: 0..47
  int n0 = (i >> 1) * 128;
  int m0 = (xcd * 2 + (i & 1)) * 128;
  __shared__ __align__(16) f16 As[128 * 32];
  __shared__ __align__(16) f16 Bs[128 * 32];
  f32x4 acc[4][4] = {};
  int t = threadIdx.x, lane = t & 63, w = t >> 6;
  int wm = (w >> 1) * 64, wn = (w & 1) * 64, lrow = lane & 15, quad = lane >> 4;
  for (int kb = 0; kb < HID / 32; ++kb) {
    stage_async(A, HID, m0, kb * 32, As);
    stage_async(B, HID, n0, kb * 32, Bs);
    __syncthreads();
    mma_tile(As, Bs, acc, wm, wn, lrow, quad);
    __syncthreads();
  }
#pragma unroll
  for (int mi = 0; mi < 4; ++mi)
#pragma unroll
    for (int ni = 0; ni < 4; ++ni)
#pragma unroll
      for (int r = 0; r < 4; ++r) {
        int row = m0 + wm + mi * 16 + quad * 4 + r;
        int col = n0 + wn + ni * 16 + lrow;
        C[(size_t)row * HID + col] = acc[mi][ni][r];
      }
}

// ---------------- RoPE on Q and K heads ----------------
__global__ void k_rope(const f16* __restrict__ qkv, const float* __restrict__ cosd,
                       const float* __restrict__ sind, f16* __restrict__ Q,
                       f16* __restrict__ Kc) {
  int idx = blockIdx.x * 256 + threadIdx.x;
  int d = idx & 127;
  int s = (idx >> 7) & (S_LEN - 1);
  int hh = idx >> 18;
  int srcCol = (hh < NH) ? hh * HD + d : HID + (hh - NH) * HD + d;
  float x = (float)qkv[(size_t)s * OPSZ + srcCol];
  float r;
  if (d < ROT) {
    float c = cosd[s * ROT + d], sn = sind[s * ROT + d];
    int pd = (d < 48) ? d + 48 : d - 48;
    float px = (float)qkv[(size_t)s * OPSZ + srcCol - d + pd];
    r = x * c + ((d < 48) ? -px : px) * sn;
  } else {
    r = x;
  }
  f16 o = (f16)r;
  if (hh < NH) Q[((size_t)hh * S_LEN + s) * HD + d] = o;
  else         Kc[((size_t)(hh - NH) * S_LEN + s) * HD + d] = o;
}

// ---------------- V transpose: Vt[8,128,2048] ----------------
__global__ void k_vt(const f16* __restrict__ qkv, f16* __restrict__ Vt) {
  __shared__ f16 tile[32][33];
  int s0 = blockIdx.x * 32, d0 = blockIdx.y * 32, kv = blockIdx.z;
  int tx = threadIdx.x & 31, ty = threadIdx.x >> 5;
#pragma unroll
  for (int i = 0; i < 4; ++i)
    tile[ty + i * 8][tx] = qkv[(size_t)(s0 + ty + i * 8) * OPSZ + 4096 + kv * HD + d0 + tx];
  __syncthreads();
#pragma unroll
  for (int i = 0; i < 4; ++i)
    Vt[((size_t)kv * HD + d0 + ty + i * 8) * S_LEN + s0 + tx] = tile[tx][ty + i * 8];
}

// ---------------- fused attention pieces ----------------
// Swizzled stage: 16B-segment XOR swizzle applied on the GLOBAL source; LDS dest
// linear (global_load_lds requirement); read side XORs the same pattern.
template <int RB, int NR, int NTHR>
__device__ __forceinline__ void stage_swz(const f16* __restrict__ G, int ld,
                                          f16* __restrict__ Ls) {
  constexpr int RPI = 1024 / RB;          // rows per 1024B wave issue
  constexpr int SEGS = RB / 16;           // 16B segments per row
  constexpr int ISSUES = (NR * RB) / ((NTHR / 64) * 1024);
  int t = threadIdx.x, lane = t & 63, w = t >> 6;
#pragma unroll
  for (int j = 0; j < ISSUES; ++j) {
    int rowBase = (w * ISSUES + j) * RPI;  // wave-uniform
    int row = rowBase + lane / SEGS;
    int gseg = (lane % SEGS) ^ (row & 7);
    const f16* gp = G + (size_t)row * ld + gseg * 8;
    f16* lp = Ls + rowBase * (RB / 2);     // wave-uniform LDS base
    __builtin_amdgcn_global_load_lds((GLOBAL_AS const void*)gp, (LDS_AS void*)lp, 16, 0, 0);
  }
}

// Pass-1 stats, KV-chunked x4 for parallelism. Grid 1536 (8 kvh x 4 chunk x 3 qh x 16 bm),
// 512 threads. Block (h,bm,c) covers KV tiles [c*8, min(c*8+8, 2(bm+1))).
// Output per q-row partial (m, l) -> stats[((h*16+bm)*4+c)*128 + row].
__global__ __launch_bounds__(512) void k_stats(const f16* __restrict__ Q,
                                               const f16* __restrict__ Kc,
                                               float2* __restrict__ stats) {
  __shared__ __align__(16) f16 Ks2[2][8192];   // 2 x 16KB K double buffer
  __shared__ float smx[4 * 128], slx[4 * 128];
  int bx = blockIdx.x;
  int kvh = bx & 7;
  int rr = bx >> 3;            // 0..191
  int c = rr & 3;
  int rr2 = rr >> 2;           // 0..47
  int qh = rr2 % 3;
  int bm = 15 - rr2 / 3;       // heavy-first
  if (c * 4 > bm) return;      // chunk fully above diagonal: inactive
  int h = kvh * NREP + qh;
  int m0 = bm * 128;
  int t0 = c * 8;
  int nt = 2 * (bm + 1);
  int t1 = (t0 + 8 < nt) ? t0 + 8 : nt;

  const f16* Qh = Q + (size_t)h * S_LEN * HD;
  const f16* Kh = Kc + (size_t)kvh * S_LEN * HD;
  int t = threadIdx.x, lane = t & 63, w = t >> 6;
  int wm = (w >> 2) * 64;      // q row-half
  int wn = (w & 3) * 16;       // t col-group (16 wide)
  int lrow = lane & 15, quad = lane >> 4;

  f16x8 qf[4][4];
#pragma unroll
  for (int kq = 0; kq < 4; ++kq)
#pragma unroll
    for (int mi = 0; mi < 4; ++mi)
      qf[kq][mi] = *reinterpret_cast<const f16x8*>(
          Qh + (size_t)(m0 + wm + mi * 16 + lrow) * HD + kq * 32 + quad * 8);

  stage_swz<256, 64, 512>(Kh + (size_t)t0 * 64 * HD, HD, Ks2[0]);

  float m1[4], l1[4];
#pragma unroll
  for (int mi = 0; mi < 4; ++mi) { m1[mi] = -1e30f; l1[mi] = 0.f; }

  for (int kt = t0; kt < t1; ++kt) {
    const char* cur = reinterpret_cast<const char*>(Ks2[(kt - t0) & 1]);
    __syncthreads();           // K(kt) arrived; pong readers done
    if (kt + 1 < t1)
      stage_swz<256, 64, 512>(Kh + (size_t)(kt + 1) * 64 * HD, HD, Ks2[(kt - t0 + 1) & 1]);
    f32x4 sacc[4] = {};
    __builtin_amdgcn_s_setprio(1);
#pragma unroll
    for (int kq = 0; kq < 4; ++kq) {
      int rowb = wn + lrow;
      f16x8 kf = *reinterpret_cast<const f16x8*>(
          cur + rowb * 256 + ((kq * 64 + quad * 16) ^ ((rowb & 7) << 4)));
#pragma unroll
      for (int mi = 0; mi < 4; ++mi)
        sacc[mi] = __builtin_amdgcn_mfma_f32_16x16x32_f16(kf, qf[kq][mi], sacc[mi], 0, 0, 0);
    }
    __builtin_amdgcn_s_setprio(0);
#pragma unroll
    for (int mi = 0; mi < 4; ++mi) {
      int qg = m0 + wm + mi * 16 + lrow;   // lane's q-row (D col = lane&15)
      float vals[4], lm = -1e30f;
#pragma unroll
      for (int r = 0; r < 4; ++r) {
        int tg = kt * 64 + wn + quad * 4 + r;
        float s = sacc[mi][r] * SCALING;
        s = (tg > qg) ? -1e30f : s;
        vals[r] = s;
        lm = fmaxf(lm, s);
      }
      lm = fmaxf(lm, __shfl_xor(lm, 16));
      lm = fmaxf(lm, __shfl_xor(lm, 32));
      float mold = m1[mi], mnew = fmaxf(mold, lm);
      float ps = 0.f;
#pragma unroll
      for (int r = 0; r < 4; ++r) ps += __expf(vals[r] - mnew);
      ps += __shfl_xor(ps, 16);
      ps += __shfl_xor(ps, 32);
      l1[mi] = l1[mi] * __expf(mold - mnew) + ps;
      m1[mi] = mnew;
    }
  }

  if (quad == 0) {
#pragma unroll
    for (int mi = 0; mi < 4; ++mi) {
      smx[(w & 3) * 128 + wm + mi * 16 + lrow] = m1[mi];
      slx[(w & 3) * 128 + wm + mi * 16 + lrow] = l1[mi];
    }
  }
  __syncthreads();
  if (t < 128) {
    float mg = smx[t];
#pragma unroll
    for (int g = 1; g < 4; ++g) mg = fmaxf(mg, smx[g * 128 + t]);
    float la = 0.f;
#pragma unroll
    for (int g = 0; g < 4; ++g) la += slx[g * 128 + t] * __expf(smx[g * 128 + t] - mg);
    float2 o; o.x = mg; o.y = la;
    stats[((size_t)(h * 16 + bm) * 4 + c) * 128 + t] = o;
  }
}

// Pass-2 with counted-vmcnt raw barriers: NT P-stores are NEVER drained in the loop.
// LDS (80KB): K0@0, K1@16KB, slots S0/S1/S2 @ 32/48/64KB.
// Per iter k (iv = 2k mod 3): QK^T reads K[k&1]; P ds_write -> S[(2k+1)%3];
// PV reads V=S[2k%3], P=S[(2k+1)%3]; stages (issued at TOP of iter k, oldest-first):
// K(k+1)->K[(k+1)&1], V(k+1)->S[(2k+2)%3]. VMEM FIFO per iter: [8 stage][32 NT store].
// B_a (iter end): s_waitcnt vmcnt(32) -> drains stages(k+1) + older stores, leaves
// newest 32 NT stores in flight. B_b (mid): lgkmcnt(0) only (P LDS visibility).
// Ledger: every buffer has a barrier between last-read and re-write (K[(k+1)&1]
// last read QK^T(k-1) < B_a(k-1); S[(2k+2)%3] last read as P in PV(k-1) < B_a(k-1);
// P slot (2k+1)%3 last read as V in PV(k-1) < B_a(k-1)).
__global__ __launch_bounds__(256, 2) void k_pv2(const f16* __restrict__ Q,
                                                const f16* __restrict__ Kc,
                                                const f16* __restrict__ Vt,
                                                const float2* __restrict__ stats,
                                                float* __restrict__ attn,
                                                f16* __restrict__ AO) {
  __shared__ __align__(16) f16 lds[5 * 8192];   // 80 KB

  int bx = blockIdx.x;
  int kvh = bx & 7;
  int rr_ = bx >> 3;            // 0..47
  int qh = rr_ % 3;
  int bm = 15 - rr_ / 3;        // heavy-first
  int h = kvh * NREP + qh;
  int m0 = bm * 128;
  int nt = 2 * (bm + 1);

  const f16* Qh = Q + (size_t)h * S_LEN * HD;
  const f16* Kh = Kc + (size_t)kvh * S_LEN * HD;
  const f16* Vh = Vt + (size_t)kvh * HD * S_LEN;
  float* attnH = attn + (size_t)h * S_LEN * S_LEN;

  int t = threadIdx.x, lane = t & 63, w = t >> 6;
  int wm = (w >> 1) * 64;       // row half (wave pair)
  int wn = (w & 1) * 32;        // col half within 64-wide KV tile
  int wn2 = (w & 1) * 64;       // col half within 128-wide PV output
  int lrow = lane & 15, quad = lane >> 4;

  // prologue stages (K0 -> K[0], V0 -> S0); latency hidden under prologue ALU
  stage_swz<256, 64, 256>(Kh, HD, lds);
  stage_swz<128, 128, 256>(Vh, S_LEN, lds + 16384);

  f16x8 qf[4][4];
#pragma unroll
  for (int kq = 0; kq < 4; ++kq)
#pragma unroll
    for (int mi = 0; mi < 4; ++mi)
      qf[kq][mi] = *reinterpret_cast<const f16x8*>(
          Qh + (size_t)(m0 + wm + mi * 16 + lrow) * HD + kq * 32 + quad * 8);

  // combine chunk partials -> final (m, 1/l) per owned row
  int nc = bm / 4 + 1;
  const float2* st = stats + (size_t)(h * 16 + bm) * 4 * 128;
  float m_f[4][4], il[4][4];
#pragma unroll
  for (int mi = 0; mi < 4; ++mi)
#pragma unroll
    for (int r2 = 0; r2 < 4; ++r2) {
      int rL = wm + mi * 16 + quad * 4 + r2;
      float mm = -1e30f, ll = 0.f;
      for (int c2 = 0; c2 < nc; ++c2) {
        float2 p = st[c2 * 128 + rL];
        float mn = fmaxf(mm, p.x);
        ll = ll * __expf(mm - mn) + p.y * __expf(p.x - mn);
        mm = mn;
      }
      m_f[mi][r2] = mm;
      il[mi][r2] = 1.0f / ll;
    }

  // B_a(0): prologue stages complete
  asm volatile("s_waitcnt vmcnt(0)" ::: "memory");
  __builtin_amdgcn_sched_barrier(0);
  __builtin_amdgcn_s_barrier();
  __builtin_amdgcn_sched_barrier(0);

  f32x4 oacc[4][4] = {};
  int iv = 0;   // = 2k mod 3
  for (int kb = 0; kb < nt; ++kb) {
    const char* Kcur = reinterpret_cast<const char*>(lds) + (size_t)(kb & 1) * 16384;
    char* Pslot = reinterpret_cast<char*>(lds) + 32768 + (size_t)((iv + 1) % 3) * 16384;
    const char* Vslot = reinterpret_cast<const char*>(lds) + 32768 + (size_t)iv * 16384;
    // early stage issue (oldest VMEM this iter; covered by QK^T+P-write+PV)
    if (kb + 1 < nt) {
      stage_swz<256, 64, 256>(Kh + (size_t)(kb + 1) * 64 * HD, HD,
                              lds + (size_t)((kb + 1) & 1) * 8192);
      stage_swz<128, 128, 256>(Vh + (size_t)(kb + 1) * 64, S_LEN,
                               lds + 16384 + (size_t)((iv + 2) % 3) * 8192);
    }
    __builtin_amdgcn_sched_barrier(0);
    // QK^T from K[kb&1]
    f32x4 sacc[4][2] = {};
    __builtin_amdgcn_s_setprio(1);
#pragma unroll
    for (int kq = 0; kq < 4; ++kq) {
      int kbyte = kq * 64 + quad * 16;
      f16x8 b[2];
#pragma unroll
      for (int ni = 0; ni < 2; ++ni) {
        int rowb = wn + ni * 16 + lrow;
        b[ni] = *reinterpret_cast<const f16x8*>(Kcur + rowb * 256 + (kbyte ^ ((rowb & 7) << 4)));
      }
#pragma unroll
      for (int mi = 0; mi < 4; ++mi)
#pragma unroll
        for (int ni = 0; ni < 2; ++ni)
          sacc[mi][ni] =
              __builtin_amdgcn_mfma_f32_16x16x32_f16(qf[kq][mi], b[ni], sacc[mi][ni], 0, 0, 0);
    }
    __builtin_amdgcn_s_setprio(0);
    // P: NT fp32 store (never drained in loop) + swizzled f16 LDS write
    int n0 = kb * 64;
#pragma unroll
    for (int mi = 0; mi < 4; ++mi)
#pragma unroll
      for (int r2 = 0; r2 < 4; ++r2) {
        int rL = wm + mi * 16 + quad * 4 + r2;
        float mm = m_f[mi][r2], ilv = il[mi][r2];
#pragma unroll
        for (int ni = 0; ni < 2; ++ni) {
          int cL = wn + ni * 16 + lrow;
          int c = n0 + cL;
          float s = sacc[mi][ni][r2] * SCALING;
          if (c > m0 + rL) s = -1e30f;
          float p = __expf(s - mm) * ilv;
          __builtin_nontemporal_store(p, attnH + (size_t)(m0 + rL) * S_LEN + c);
          *reinterpret_cast<f16*>(Pslot + rL * 128 + ((cL * 2) ^ ((rL & 7) << 4))) = (f16)p;
        }
      }
    // B_b: P LDS visible to all waves; NO vmcnt drain (NT stores stay in flight)
    asm volatile("s_waitcnt lgkmcnt(0)" ::: "memory");
    __builtin_amdgcn_sched_barrier(0);
    __builtin_amdgcn_s_barrier();
    __builtin_amdgcn_sched_barrier(0);
    // PV from P slot + V slot
    __builtin_amdgcn_s_setprio(1);
#pragma unroll
    for (int kq = 0; kq < 2; ++kq) {
      int kbyte = kq * 64 + quad * 16;
      f16x8 a[4], b[4];
#pragma unroll
      for (int mi = 0; mi < 4; ++mi) {
        int rowp = wm + mi * 16 + lrow;
        a[mi] = *reinterpret_cast<const f16x8*>(Pslot + rowp * 128 + (kbyte ^ ((rowp & 7) << 4)));
      }
#pragma unroll
      for (int ni = 0; ni < 4; ++ni) {
        int rowv = wn2 + ni * 16 + lrow;
        b[ni] = *reinterpret_cast<const f16x8*>(Vslot + rowv * 128 + (kbyte ^ ((rowv & 7) << 4)));
      }
#pragma unroll
      for (int mi = 0; mi < 4; ++mi)
#pragma unroll
        for (int ni = 0; ni < 4; ++ni)
          oacc[mi][ni] =
              __builtin_amdgcn_mfma_f32_16x16x32_f16(a[mi], b[ni], oacc[mi][ni], 0, 0, 0);
    }
    __builtin_amdgcn_s_setprio(0);
    // B_a(kb+1): stages done (counted — leaves newest 32 NT stores in flight)
    if (kb + 1 < nt) {
      asm volatile("s_waitcnt vmcnt(32)" ::: "memory");
      __builtin_amdgcn_sched_barrier(0);
      __builtin_amdgcn_s_barrier();
      __builtin_amdgcn_sched_barrier(0);
    }
    iv = (iv + 2) % 3;
  }

  // AO epilogue (re-read by gemm_out: keep cached)
#pragma unroll
  for (int mi = 0; mi < 4; ++mi)
#pragma unroll
    for (int ni = 0; ni < 4; ++ni)
#pragma unroll
      for (int r = 0; r < 4; ++r) {
        int row = m0 + wm + mi * 16 + quad * 4 + r;
        int col = wn2 + ni * 16 + lrow;
        AO[(size_t)row * HID + h * HD + col] = (f16)oacc[mi][ni][r];
      }

  // zero-fill fully masked cols >= (bm+1)*128 (nontemporal)
  f32x4 z = {0.f, 0.f, 0.f, 0.f};
  for (int zt = bm + 1; zt < 16; ++zt) {
    float* outp = attnH + (size_t)m0 * S_LEN + zt * 128;
#pragma unroll
    for (int j = 0; j < 16; ++j) {
      int lin = t + 256 * j;
      int rowz = lin >> 5, seg = lin & 31;
      __builtin_nontemporal_store(z, reinterpret_cast<f32x4*>(outp + (size_t)rowz * S_LEN) + seg);
    }
  }
}

// ---------------- launch ----------------
extern "C" void kernel_launch(void* const* d_in, const int* in_sizes, int n_in,
                              void* d_out, int out_size, void* d_ws, size_t ws_size,
                              hipStream_t stream) {
  const float* hs    = (const float*)d_in[0];
  const float* cosd  = (const float*)d_in[1];
  const float* sind  = (const float*)d_in[2];
  // d_in[3] = attention_mask (causal by construction; unused)
  const float* w_qkv = (const float*)d_in[4];
  const float* w_o   = (const float*)d_in[5];

  float* out  = (float*)d_out;
  float* attn = out + (size_t)S_LEN * HID;

  char* ws = (char*)d_ws;
  f16* hs16   = (f16*)(ws + 0);          // reused later as AO
  f16* wq16   = (f16*)(ws + 12582912);   // reused later as Wo16 (+ stats tail)
  f16* qkv16  = (f16*)(ws + 44040192);
  f16* Q16    = (f16*)(ws + 65011712);
  f16* K16    = (f16*)(ws + 77594624);
  f16* Vt16   = (f16*)(ws + 81788928);
  f16* AO16   = hs16;
  f16* Wo16   = wq16;
  // stats: 24*16*4*128 float2 = 1.5 MB; lives in wq16 tail after Wo16 (18,874,368 B).
  float2* stats = (float2*)(ws + 12582912 + 18874368);

  k_cast4<<<6144, 256, 0, stream>>>(hs, hs16, (S_LEN * HID) / 4);
  k_cast4<<<15360, 256, 0, stream>>>(w_qkv, wq16, (OPSZ * HID) / 4);
  k_gemm_qkv<<<640, 256, 0, stream>>>(hs16, wq16, qkv16);
  k_rope<<<32768, 256, 0, stream>>>(qkv16, cosd, sind, Q16, K16);
  k_vt<<<dim3(64, 4, 8), 256, 0, stream>>>(qkv16, Vt16);
  k_cast4<<<9216, 256, 0, stream>>>(w_o, Wo16, (HID * HID) / 4);
  // attention: chunked stats, then fused P-write + PV (counted-vmcnt pipeline)
  k_stats<<<1536, 512, 0, stream>>>(Q16, K16, stats);
  k_pv2<<<384, 256, 0, stream>>>(Q16, K16, Vt16, stats, attn, AO16);
  k_gemm_out<<<384, 256, 0, stream>>>(AO16, Wo16, out);
}

// Round 8
// 809.649 us; speedup vs baseline: 1.5605x; 1.2179x over previous
//
#include <hip/hip_runtime.h>
#include <cstdint>
#include <cstddef>

#define S_LEN 2048
#define HID   3072
#define NH    24
#define NKV   8
#define HD    128
#define ROT   96
#define OPSZ  5120   // NH*HD + 2*NKV*HD
#define NREP  3      // NH/NKV
#define SCALING 0.08838834764831845f

typedef _Float16 f16;
typedef float f32x4 __attribute__((ext_vector_type(4)));
typedef _Float16 f16x8 __attribute__((ext_vector_type(8)));
typedef _Float16 f16x4 __attribute__((ext_vector_type(4)));

#define GLOBAL_AS __attribute__((address_space(1)))
#define LDS_AS    __attribute__((address_space(3)))

// ---------------- cast fp32 -> fp16 (4 elems/thread) ----------------
__global__ void k_cast4(const float* __restrict__ in, f16* __restrict__ out, int n4) {
  int i = blockIdx.x * blockDim.x + threadIdx.x;
  if (i >= n4) return;
  float4 v = reinterpret_cast<const float4*>(in)[i];
  f16x4 o = {(f16)v.x, (f16)v.y, (f16)v.z, (f16)v.w};
  reinterpret_cast<f16x4*>(out)[i] = o;
}

// ---------------- GEMM building blocks ----------------
__device__ __forceinline__ void stage_async(const f16* __restrict__ G, int ld, int m0, int k0,
                                            f16* __restrict__ Ls) {
  int t = threadIdx.x;
  int lane = t & 63, w = t >> 6;
#pragma unroll
  for (int j = 0; j < 2; ++j) {
    int rowBase = w * 16 + j * 64;            // wave-uniform
    int row = rowBase + (lane >> 2);
    int seg = lane & 3;
    const f16* gp = G + (size_t)(m0 + row) * ld + k0 + seg * 8;
    f16* lp = Ls + rowBase * 32;              // wave-uniform LDS base
    __builtin_amdgcn_global_load_lds((GLOBAL_AS const void*)gp, (LDS_AS void*)lp, 16, 0, 0);
  }
}

__device__ __forceinline__ void mma_tile(const f16* __restrict__ As, const f16* __restrict__ Bs,
                                         f32x4 acc[4][4], int wm, int wn, int lrow, int quad) {
  f16x8 a[4], b[4];
#pragma unroll
  for (int mi = 0; mi < 4; ++mi)
    a[mi] = *reinterpret_cast<const f16x8*>(As + (wm + mi * 16 + lrow) * 32 + quad * 8);
#pragma unroll
  for (int ni = 0; ni < 4; ++ni)
    b[ni] = *reinterpret_cast<const f16x8*>(Bs + (wn + ni * 16 + lrow) * 32 + quad * 8);
#pragma unroll
  for (int mi = 0; mi < 4; ++mi)
#pragma unroll
    for (int ni = 0; ni < 4; ++ni)
      acc[mi][ni] = __builtin_amdgcn_mfma_f32_16x16x32_f16(a[mi], b[ni], acc[mi][ni], 0, 0, 0);
}

// ---------------- QKV GEMM (XCD-swizzled 1-D grid: 640 = 8 xcd * 40 n * 2 m) ----------------
__global__ __launch_bounds__(256) void k_gemm_qkv(const f16* __restrict__ A,
                                                  const f16* __restrict__ B,
                                                  f16* __restrict__ C) {
  int bx = blockIdx.x;
  int xcd = bx & 7, i = bx >> 3;               // i: 0..79
  int n0 = (i >> 1) * 128;                     // n-major within XCD
  int m0 = (xcd * 2 + (i & 1)) * 128;          // 2 m-blocks pinned per XCD
  __shared__ __align__(16) f16 As[128 * 32];
  __shared__ __align__(16) f16 Bs[128 * 32];
  f32x4 acc[4][4] = {};
  int t = threadIdx.x, lane = t & 63, w = t >> 6;
  int wm = (w >> 1) * 64, wn = (w & 1) * 64, lrow = lane & 15, quad = lane >> 4;
  for (int kb = 0; kb < HID / 32; ++kb) {
    stage_async(A, HID, m0, kb * 32, As);
    stage_async(B, HID, n0, kb * 32, Bs);
    __syncthreads();
    mma_tile(As, Bs, acc, wm, wn, lrow, quad);
    __syncthreads();
  }
#pragma unroll
  for (int mi = 0; mi < 4; ++mi)
#pragma unroll
    for (int ni = 0; ni < 4; ++ni)
#pragma unroll
      for (int r = 0; r < 4; ++r) {
        int row = m0 + wm + mi * 16 + quad * 4 + r;
        int col = n0 + wn + ni * 16 + lrow;
        C[(size_t)row * OPSZ + col] = (f16)acc[mi][ni][r];
      }
}

// ---------------- out proj (XCD-swizzled 1-D grid: 384 = 8 xcd * 24 n * 2 m) ----------------
__global__ __launch_bounds__(256) void k_gemm_out(const f16* __restrict__ A,
                                                  const f16* __restrict__ B,
                                                  float* __restrict__ C) {
  int bx = blockIdx.x;
  int xcd = bx & 7, i = bx >> 3;               // i: 0..47
  int n0 = (i >> 1) * 128;
  int m0 = (xcd * 2 + (i & 1)) * 128;
  __shared__ __align__(16) f16 As[128 * 32];
  __shared__ __align__(16) f16 Bs[128 * 32];
  f32x4 acc[4][4] = {};
  int t = threadIdx.x, lane = t & 63, w = t >> 6;
  int wm = (w >> 1) * 64, wn = (w & 1) * 64, lrow = lane & 15, quad = lane >> 4;
  for (int kb = 0; kb < HID / 32; ++kb) {
    stage_async(A, HID, m0, kb * 32, As);
    stage_async(B, HID, n0, kb * 32, Bs);
    __syncthreads();
    mma_tile(As, Bs, acc, wm, wn, lrow, quad);
    __syncthreads();
  }
#pragma unroll
  for (int mi = 0; mi < 4; ++mi)
#pragma unroll
    for (int ni = 0; ni < 4; ++ni)
#pragma unroll
      for (int r = 0; r < 4; ++r) {
        int row = m0 + wm + mi * 16 + quad * 4 + r;
        int col = n0 + wn + ni * 16 + lrow;
        C[(size_t)row * HID + col] = acc[mi][ni][r];
      }
}

// ---------------- RoPE on Q and K heads ----------------
__global__ void k_rope(const f16* __restrict__ qkv, const float* __restrict__ cosd,
                       const float* __restrict__ sind, f16* __restrict__ Q,
                       f16* __restrict__ Kc) {
  int idx = blockIdx.x * 256 + threadIdx.x;
  int d = idx & 127;
  int s = (idx >> 7) & (S_LEN - 1);
  int hh = idx >> 18;
  int srcCol = (hh < NH) ? hh * HD + d : HID + (hh - NH) * HD + d;
  float x = (float)qkv[(size_t)s * OPSZ + srcCol];
  float r;
  if (d < ROT) {
    float c = cosd[s * ROT + d], sn = sind[s * ROT + d];
    int pd = (d < 48) ? d + 48 : d - 48;
    float px = (float)qkv[(size_t)s * OPSZ + srcCol - d + pd];
    r = x * c + ((d < 48) ? -px : px) * sn;
  } else {
    r = x;
  }
  f16 o = (f16)r;
  if (hh < NH) Q[((size_t)hh * S_LEN + s) * HD + d] = o;
  else         Kc[((size_t)(hh - NH) * S_LEN + s) * HD + d] = o;
}

// ---------------- V transpose: Vt[8,128,2048] ----------------
__global__ void k_vt(const f16* __restrict__ qkv, f16* __restrict__ Vt) {
  __shared__ f16 tile[32][33];
  int s0 = blockIdx.x * 32, d0 = blockIdx.y * 32, kv = blockIdx.z;
  int tx = threadIdx.x & 31, ty = threadIdx.x >> 5;
#pragma unroll
  for (int i = 0; i < 4; ++i)
    tile[ty + i * 8][tx] = qkv[(size_t)(s0 + ty + i * 8) * OPSZ + 4096 + kv * HD + d0 + tx];
  __syncthreads();
#pragma unroll
  for (int i = 0; i < 4; ++i)
    Vt[((size_t)kv * HD + d0 + ty + i * 8) * S_LEN + s0 + tx] = tile[tx][ty + i * 8];
}

// ---------------- fused attention pieces ----------------
// Swizzled stage: 16B-segment XOR swizzle applied on the GLOBAL source; LDS dest
// linear (global_load_lds requirement); read side XORs the same pattern.
template <int RB, int NR, int NTHR>
__device__ __forceinline__ void stage_swz(const f16* __restrict__ G, int ld,
                                          f16* __restrict__ Ls) {
  constexpr int RPI = 1024 / RB;          // rows per 1024B wave issue
  constexpr int SEGS = RB / 16;           // 16B segments per row
  constexpr int ISSUES = (NR * RB) / ((NTHR / 64) * 1024);
  int t = threadIdx.x, lane = t & 63, w = t >> 6;
#pragma unroll
  for (int j = 0; j < ISSUES; ++j) {
    int rowBase = (w * ISSUES + j) * RPI;  // wave-uniform
    int row = rowBase + lane / SEGS;
    int gseg = (lane % SEGS) ^ (row & 7);
    const f16* gp = G + (size_t)row * ld + gseg * 8;
    f16* lp = Ls + rowBase * (RB / 2);     // wave-uniform LDS base
    __builtin_amdgcn_global_load_lds((GLOBAL_AS const void*)gp, (LDS_AS void*)lp, 16, 0, 0);
  }
}

// Pass-1 stats, KV-chunked x4 for parallelism. Grid 1536 (8 kvh x 4 chunk x 3 qh x 16 bm),
// 512 threads. Block (h,bm,c) covers KV tiles [c*8, min(c*8+8, 2(bm+1))).
// Output per q-row partial (m, l) -> stats[((h*16+bm)*4+c)*128 + row].
__global__ __launch_bounds__(512) void k_stats(const f16* __restrict__ Q,
                                               const f16* __restrict__ Kc,
                                               float2* __restrict__ stats) {
  __shared__ __align__(16) f16 Ks2[2][8192];   // 2 x 16KB K double buffer
  __shared__ float smx[4 * 128], slx[4 * 128];
  int bx = blockIdx.x;
  int kvh = bx & 7;
  int rr = bx >> 3;            // 0..191
  int c = rr & 3;
  int rr2 = rr >> 2;           // 0..47
  int qh = rr2 % 3;
  int bm = 15 - rr2 / 3;       // heavy-first
  if (c * 4 > bm) return;      // chunk fully above diagonal: inactive
  int h = kvh * NREP + qh;
  int m0 = bm * 128;
  int t0 = c * 8;
  int nt = 2 * (bm + 1);
  int t1 = (t0 + 8 < nt) ? t0 + 8 : nt;

  const f16* Qh = Q + (size_t)h * S_LEN * HD;
  const f16* Kh = Kc + (size_t)kvh * S_LEN * HD;
  int t = threadIdx.x, lane = t & 63, w = t >> 6;
  int wm = (w >> 2) * 64;      // q row-half
  int wn = (w & 3) * 16;       // t col-group (16 wide)
  int lrow = lane & 15, quad = lane >> 4;

  f16x8 qf[4][4];
#pragma unroll
  for (int kq = 0; kq < 4; ++kq)
#pragma unroll
    for (int mi = 0; mi < 4; ++mi)
      qf[kq][mi] = *reinterpret_cast<const f16x8*>(
          Qh + (size_t)(m0 + wm + mi * 16 + lrow) * HD + kq * 32 + quad * 8);

  stage_swz<256, 64, 512>(Kh + (size_t)t0 * 64 * HD, HD, Ks2[0]);

  float m1[4], l1[4];
#pragma unroll
  for (int mi = 0; mi < 4; ++mi) { m1[mi] = -1e30f; l1[mi] = 0.f; }

  for (int kt = t0; kt < t1; ++kt) {
    const char* cur = reinterpret_cast<const char*>(Ks2[(kt - t0) & 1]);
    __syncthreads();           // K(kt) arrived; pong readers done
    if (kt + 1 < t1)
      stage_swz<256, 64, 512>(Kh + (size_t)(kt + 1) * 64 * HD, HD, Ks2[(kt - t0 + 1) & 1]);
    f32x4 sacc[4] = {};
    __builtin_amdgcn_s_setprio(1);
#pragma unroll
    for (int kq = 0; kq < 4; ++kq) {
      int rowb = wn + lrow;
      f16x8 kf = *reinterpret_cast<const f16x8*>(
          cur + rowb * 256 + ((kq * 64 + quad * 16) ^ ((rowb & 7) << 4)));
#pragma unroll
      for (int mi = 0; mi < 4; ++mi)
        sacc[mi] = __builtin_amdgcn_mfma_f32_16x16x32_f16(kf, qf[kq][mi], sacc[mi], 0, 0, 0);
    }
    __builtin_amdgcn_s_setprio(0);
#pragma unroll
    for (int mi = 0; mi < 4; ++mi) {
      int qg = m0 + wm + mi * 16 + lrow;   // lane's q-row (D col = lane&15)
      float vals[4], lm = -1e30f;
#pragma unroll
      for (int r = 0; r < 4; ++r) {
        int tg = kt * 64 + wn + quad * 4 + r;
        float s = sacc[mi][r] * SCALING;
        s = (tg > qg) ? -1e30f : s;
        vals[r] = s;
        lm = fmaxf(lm, s);
      }
      lm = fmaxf(lm, __shfl_xor(lm, 16));
      lm = fmaxf(lm, __shfl_xor(lm, 32));
      float mold = m1[mi], mnew = fmaxf(mold, lm);
      float ps = 0.f;
#pragma unroll
      for (int r = 0; r < 4; ++r) ps += __expf(vals[r] - mnew);
      ps += __shfl_xor(ps, 16);
      ps += __shfl_xor(ps, 32);
      l1[mi] = l1[mi] * __expf(mold - mnew) + ps;
      m1[mi] = mnew;
    }
  }

  if (quad == 0) {
#pragma unroll
    for (int mi = 0; mi < 4; ++mi) {
      smx[(w & 3) * 128 + wm + mi * 16 + lrow] = m1[mi];
      slx[(w & 3) * 128 + wm + mi * 16 + lrow] = l1[mi];
    }
  }
  __syncthreads();
  if (t < 128) {
    float mg = smx[t];
#pragma unroll
    for (int g = 1; g < 4; ++g) mg = fmaxf(mg, smx[g * 128 + t]);
    float la = 0.f;
#pragma unroll
    for (int g = 0; g < 4; ++g) la += slx[g * 128 + t] * __expf(smx[g * 128 + t] - mg);
    float2 o; o.x = mg; o.y = la;
    stats[((size_t)(h * 16 + bm) * 4 + c) * 128 + t] = o;
  }
}

// Pass-2 with swapped QK^T (mfma(K,Q): lane owns q-row = lrow, regs = 4 consecutive
// t-cols) so P goes out as float4 REGULAR stores (8/thread/iter, L2-coalesced)
// and into LDS as f16x4. Counted-vmcnt raw barriers kept from r7:
// per iter per thread VMEM = 8 stages (issued at top) + 8 stores (mid).
// B_a (iter end): vmcnt(8) -> drains stages(k+1)+older, leaves 8 newest stores.
// B_b (mid): lgkmcnt(0) only (P LDS visibility). Slot ledger as r7 (audited).
__global__ __launch_bounds__(256, 2) void k_pv2(const f16* __restrict__ Q,
                                                const f16* __restrict__ Kc,
                                                const f16* __restrict__ Vt,
                                                const float2* __restrict__ stats,
                                                float* __restrict__ attn,
                                                f16* __restrict__ AO) {
  __shared__ __align__(16) f16 lds[5 * 8192];   // 80 KB

  int bx = blockIdx.x;
  int kvh = bx & 7;
  int rr_ = bx >> 3;            // 0..47
  int qh = rr_ % 3;
  int bm = 15 - rr_ / 3;        // heavy-first
  int h = kvh * NREP + qh;
  int m0 = bm * 128;
  int nt = 2 * (bm + 1);

  const f16* Qh = Q + (size_t)h * S_LEN * HD;
  const f16* Kh = Kc + (size_t)kvh * S_LEN * HD;
  const f16* Vh = Vt + (size_t)kvh * HD * S_LEN;
  float* attnH = attn + (size_t)h * S_LEN * S_LEN;

  int t = threadIdx.x, lane = t & 63, w = t >> 6;
  int wm = (w >> 1) * 64;       // q row half
  int wn = (w & 1) * 32;        // t col half within 64-wide KV tile
  int wn2 = (w & 1) * 64;       // col half within 128-wide PV output
  int lrow = lane & 15, quad = lane >> 4;

  // prologue stages (K0 -> K[0], V0 -> S0); latency hidden under prologue ALU
  stage_swz<256, 64, 256>(Kh, HD, lds);
  stage_swz<128, 128, 256>(Vh, S_LEN, lds + 16384);

  f16x8 qf[4][4];
#pragma unroll
  for (int kq = 0; kq < 4; ++kq)
#pragma unroll
    for (int mi = 0; mi < 4; ++mi)
      qf[kq][mi] = *reinterpret_cast<const f16x8*>(
          Qh + (size_t)(m0 + wm + mi * 16 + lrow) * HD + kq * 32 + quad * 8);

  // combine chunk partials -> final (m, 1/l); lane's q-row = wm + mi*16 + lrow
  int nc = bm / 4 + 1;
  const float2* st = stats + (size_t)(h * 16 + bm) * 4 * 128;
  float m_f[4], il[4];
#pragma unroll
  for (int mi = 0; mi < 4; ++mi) {
    int rL = wm + mi * 16 + lrow;
    float mm = -1e30f, ll = 0.f;
    for (int c2 = 0; c2 < nc; ++c2) {
      float2 p = st[c2 * 128 + rL];
      float mn = fmaxf(mm, p.x);
      ll = ll * __expf(mm - mn) + p.y * __expf(p.x - mn);
      mm = mn;
    }
    m_f[mi] = mm;
    il[mi] = 1.0f / ll;
  }

  // B_a(0): prologue stages complete
  asm volatile("s_waitcnt vmcnt(0)" ::: "memory");
  __builtin_amdgcn_sched_barrier(0);
  __builtin_amdgcn_s_barrier();
  __builtin_amdgcn_sched_barrier(0);

  f32x4 oacc[4][4] = {};
  int iv = 0;   // = 2k mod 3
  for (int kb = 0; kb < nt; ++kb) {
    const char* Kcur = reinterpret_cast<const char*>(lds) + (size_t)(kb & 1) * 16384;
    char* Pslot = reinterpret_cast<char*>(lds) + 32768 + (size_t)((iv + 1) % 3) * 16384;
    const char* Vslot = reinterpret_cast<const char*>(lds) + 32768 + (size_t)iv * 16384;
    // early stage issue (oldest VMEM this iter; covered by QK^T+P-write+PV)
    if (kb + 1 < nt) {
      stage_swz<256, 64, 256>(Kh + (size_t)(kb + 1) * 64 * HD, HD,
                              lds + (size_t)((kb + 1) & 1) * 8192);
      stage_swz<128, 128, 256>(Vh + (size_t)(kb + 1) * 64, S_LEN,
                               lds + 16384 + (size_t)((iv + 2) % 3) * 8192);
    }
    __builtin_amdgcn_sched_barrier(0);
    // QK^T swapped: mfma(K, Q) -> lane q-row = lrow, regs = t quad*4+r
    f32x4 sacc[4][2] = {};
    __builtin_amdgcn_s_setprio(1);
#pragma unroll
    for (int kq = 0; kq < 4; ++kq) {
      int kbyte = kq * 64 + quad * 16;
      f16x8 b[2];
#pragma unroll
      for (int ni = 0; ni < 2; ++ni) {
        int rowb = wn + ni * 16 + lrow;
        b[ni] = *reinterpret_cast<const f16x8*>(Kcur + rowb * 256 + (kbyte ^ ((rowb & 7) << 4)));
      }
#pragma unroll
      for (int mi = 0; mi < 4; ++mi)
#pragma unroll
        for (int ni = 0; ni < 2; ++ni)
          sacc[mi][ni] =
              __builtin_amdgcn_mfma_f32_16x16x32_f16(b[ni], qf[kq][mi], sacc[mi][ni], 0, 0, 0);
    }
    __builtin_amdgcn_s_setprio(0);
    // P: float4 regular store (L2-coalesced) + f16x4 swizzled LDS write
    int n0 = kb * 64;
#pragma unroll
    for (int mi = 0; mi < 4; ++mi) {
      int rL = wm + mi * 16 + lrow;
      int qg = m0 + rL;
      float mm = m_f[mi], ilv = il[mi];
#pragma unroll
      for (int ni = 0; ni < 2; ++ni) {
        int cL = wn + ni * 16 + quad * 4;
        int tb = n0 + cL;
        f32x4 pv4;
        f16x4 ph4;
#pragma unroll
        for (int r = 0; r < 4; ++r) {
          float s = sacc[mi][ni][r] * SCALING;
          if (tb + r > qg) s = -1e30f;
          float p = __expf(s - mm) * ilv;
          pv4[r] = p;
          ph4[r] = (f16)p;
        }
        *reinterpret_cast<f32x4*>(attnH + (size_t)qg * S_LEN + tb) = pv4;
        *reinterpret_cast<f16x4*>(Pslot + rL * 128 + ((cL * 2) ^ ((rL & 7) << 4))) = ph4;
      }
    }
    // B_b: P LDS visible to all waves; no vmcnt drain (stores stay in flight)
    asm volatile("s_waitcnt lgkmcnt(0)" ::: "memory");
    __builtin_amdgcn_sched_barrier(0);
    __builtin_amdgcn_s_barrier();
    __builtin_amdgcn_sched_barrier(0);
    // PV from P slot + V slot (unchanged orientation)
    __builtin_amdgcn_s_setprio(1);
#pragma unroll
    for (int kq = 0; kq < 2; ++kq) {
      int kbyte = kq * 64 + quad * 16;
      f16x8 a[4], b[4];
#pragma unroll
      for (int mi = 0; mi < 4; ++mi) {
        int rowp = wm + mi * 16 + lrow;
        a[mi] = *reinterpret_cast<const f16x8*>(Pslot + rowp * 128 + (kbyte ^ ((rowp & 7) << 4)));
      }
#pragma unroll
      for (int ni = 0; ni < 4; ++ni) {
        int rowv = wn2 + ni * 16 + lrow;
        b[ni] = *reinterpret_cast<const f16x8*>(Vslot + rowv * 128 + (kbyte ^ ((rowv & 7) << 4)));
      }
#pragma unroll
      for (int mi = 0; mi < 4; ++mi)
#pragma unroll
        for (int ni = 0; ni < 4; ++ni)
          oacc[mi][ni] =
              __builtin_amdgcn_mfma_f32_16x16x32_f16(a[mi], b[ni], oacc[mi][ni], 0, 0, 0);
    }
    __builtin_amdgcn_s_setprio(0);
    // B_a(kb+1): stages done (vmcnt(8) leaves this iter's 8 stores in flight)
    if (kb + 1 < nt) {
      asm volatile("s_waitcnt vmcnt(8)" ::: "memory");
      __builtin_amdgcn_sched_barrier(0);
      __builtin_amdgcn_s_barrier();
      __builtin_amdgcn_sched_barrier(0);
    }
    iv = (iv + 2) % 3;
  }

  // AO epilogue (re-read by gemm_out: keep cached)
#pragma unroll
  for (int mi = 0; mi < 4; ++mi)
#pragma unroll
    for (int ni = 0; ni < 4; ++ni)
#pragma unroll
      for (int r = 0; r < 4; ++r) {
        int row = m0 + wm + mi * 16 + quad * 4 + r;
        int col = wn2 + ni * 16 + lrow;
        AO[(size_t)row * HID + h * HD + col] = (f16)oacc[mi][ni][r];
      }

  // zero-fill fully masked cols >= (bm+1)*128 (regular full-line stores)
  f32x4 z = {0.f, 0.f, 0.f, 0.f};
  for (int zt = bm + 1; zt < 16; ++zt) {
    float* outp = attnH + (size_t)m0 * S_LEN + zt * 128;
#pragma unroll
    for (int j = 0; j < 16; ++j) {
      int lin = t + 256 * j;
      int rowz = lin >> 5, seg = lin & 31;
      reinterpret_cast<f32x4*>(outp + (size_t)rowz * S_LEN)[seg] = z;
    }
  }
}

// ---------------- launch ----------------
extern "C" void kernel_launch(void* const* d_in, const int* in_sizes, int n_in,
                              void* d_out, int out_size, void* d_ws, size_t ws_size,
                              hipStream_t stream) {
  const float* hs    = (const float*)d_in[0];
  const float* cosd  = (const float*)d_in[1];
  const float* sind  = (const float*)d_in[2];
  // d_in[3] = attention_mask (causal by construction; unused)
  const float* w_qkv = (const float*)d_in[4];
  const float* w_o   = (const float*)d_in[5];

  float* out  = (float*)d_out;
  float* attn = out + (size_t)S_LEN * HID;

  char* ws = (char*)d_ws;
  f16* hs16   = (f16*)(ws + 0);          // reused later as AO
  f16* wq16   = (f16*)(ws + 12582912);   // reused later as Wo16 (+ stats tail)
  f16* qkv16  = (f16*)(ws + 44040192);
  f16* Q16    = (f16*)(ws + 65011712);
  f16* K16    = (f16*)(ws + 77594624);
  f16* Vt16   = (f16*)(ws + 81788928);
  f16* AO16   = hs16;
  f16* Wo16   = wq16;
  // stats: 24*16*4*128 float2 = 1.5 MB; lives in wq16 tail after Wo16 (18,874,368 B).
  float2* stats = (float2*)(ws + 12582912 + 18874368);

  k_cast4<<<6144, 256, 0, stream>>>(hs, hs16, (S_LEN * HID) / 4);
  k_cast4<<<15360, 256, 0, stream>>>(w_qkv, wq16, (OPSZ * HID) / 4);
  k_gemm_qkv<<<640, 256, 0, stream>>>(hs16, wq16, qkv16);
  k_rope<<<32768, 256, 0, stream>>>(qkv16, cosd, sind, Q16, K16);
  k_vt<<<dim3(64, 4, 8), 256, 0, stream>>>(qkv16, Vt16);
  k_cast4<<<9216, 256, 0, stream>>>(w_o, Wo16, (HID * HID) / 4);
  // attention: chunked stats, then fused P-write + PV (counted-vmcnt pipeline)
  k_stats<<<1536, 512, 0, stream>>>(Q16, K16, stats);
  k_pv2<<<384, 256, 0, stream>>>(Q16, K16, Vt16, stats, attn, AO16);
  k_gemm_out<<<384, 256, 0, stream>>>(AO16, Wo16, out);
}